// Round 1
// baseline (3628.873 us; speedup 1.0000x reference)
//
#include <hip/hip_runtime.h>
#include <hip/hip_bf16.h>

typedef unsigned short u16;
typedef unsigned int   u32;

typedef __attribute__((ext_vector_type(8))) short short8;
typedef __attribute__((ext_vector_type(4))) float f32x4;

typedef const __attribute__((address_space(1))) void g_void;
typedef __attribute__((address_space(3))) void l_void;

__device__ __forceinline__ float bf2f(u16 u) {
    u32 x = ((u32)u) << 16;
    return __builtin_bit_cast(float, x);
}
__device__ __forceinline__ u16 f2bf(float f) {
    u32 u = __builtin_bit_cast(u32, f);
    u32 r = (u + 0x7FFFu + ((u >> 16) & 1u)) >> 16;
    return (u16)r;
}
__device__ __forceinline__ u32 pack2(float a, float b) {
    return (u32)f2bf(a) | ((u32)f2bf(b) << 16);
}

// ---------------------------------------------------------------------------
// Dtype detector: reads first 16384 u16 words of X. bf16 data -> ~100% sane
// exponent fields; fp32 data reinterpreted as u16 -> ~57%. flags[0]=1 => fp32.
// flags[1] is a guaranteed-zero word used by consumers needing "always bf16".
// ---------------------------------------------------------------------------
__global__ void detect_kernel(const u16* __restrict__ X, int* __restrict__ flags) {
    __shared__ int cnt[256];
    int c = 0;
    for (int i = threadIdx.x; i < 16384; i += 256) {
        u16 v = X[i];
        int e = (v >> 7) & 0xFF;
        c += (e >= 104 && e <= 140) ? 1 : 0;
    }
    cnt[threadIdx.x] = c;
    __syncthreads();
    for (int s = 128; s > 0; s >>= 1) {
        if (threadIdx.x < s) cnt[threadIdx.x] += cnt[threadIdx.x + s];
        __syncthreads();
    }
    if (threadIdx.x == 0) {
        flags[0] = (cnt[0] < 14746) ? 1 : 0;   // <90% sane => fp32
        flags[1] = 0;
    }
}

// X canonicalization: only does work when input is fp32 (copies to bf16 XC).
__global__ __launch_bounds__(256) void convert_x(const float* __restrict__ Xf,
                                                 u16* __restrict__ XC,
                                                 const int* __restrict__ flags, int n) {
    if (flags[0] == 0) return;
    int i = (blockIdx.x * 256 + threadIdx.x) * 8;
    if (i >= n) return;
    float4 a = *(const float4*)(Xf + i);
    float4 b = *(const float4*)(Xf + i + 4);
    uint4 o;
    o.x = pack2(a.x, a.y); o.y = pack2(a.z, a.w);
    o.z = pack2(b.x, b.y); o.w = pack2(b.z, b.w);
    *(uint4*)(XC + i) = o;
}

// mask canonicalization to fp32 (always runs; tiny).
__global__ void convert_mask(const void* __restrict__ m, float* __restrict__ MC,
                             const int* __restrict__ flags, int n) {
    int i = blockIdx.x * 256 + threadIdx.x;
    if (i >= n) return;
    MC[i] = flags[0] ? ((const float*)m)[i] : bf2f(((const u16*)m)[i]);
}

// ---------------------------------------------------------------------------
// GEMM: C(MxN, ldc) = A(MxK, bf16, lda) * Bt(NxK, bf16, ldb)^T
// 128x128 tile, BK=32, 4 waves (2x2), 16x16x32 bf16 MFMA.
// Staging via global_load_lds width=16: LDS dest is linear in lane
// (wave-uniform base + lane*16); the conflict-avoiding swizzle lives on the
// per-lane GLOBAL source address (slot s holds chunk s ^ swz(row)), so the
// fragment-read swizzle below is unchanged from the reg-staging version.
// A chosen between A0/A1 by aselp[0]; C stored bf16 or fp32 per ofp[0].
// ---------------------------------------------------------------------------
__global__ __launch_bounds__(256) void gemm_bt(
    const u16* __restrict__ A0, const u16* __restrict__ A1, int lda,
    const u16* __restrict__ Bt, int ldb,
    void* __restrict__ C, int ldc,
    int Mtiles, int K,
    const int* __restrict__ aselp, const int* __restrict__ ofp) {
    __shared__ char smem[16384];

    const u16* A = aselp[0] ? A1 : A0;

    const int tid = threadIdx.x;
    const int w = tid >> 6, lane = tid & 63;
    const int mt = blockIdx.x % Mtiles;
    const int nt = blockIdx.x / Mtiles;
    const int m0 = mt << 7, n0 = nt << 7;
    const int wm = w >> 1, wn = w & 1;

    f32x4 acc[4][4] = {};

    // staging: row rr = w*16 + lane/4 (plus +64 for second store),
    // LDS slot s = lane&3 holds global chunk cg = s ^ swz(row), swz(r)=(r>>1)&3
    const int rr = w * 16 + (lane >> 2);
    const int cg = (lane & 3) ^ ((lane >> 3) & 3);

    const u16* gA0 = A + (m0 + rr) * lda + cg * 8;
    const u16* gA1 = A + (m0 + rr + 64) * lda + cg * 8;
    const u16* gB0 = Bt + (n0 + rr) * ldb + cg * 8;
    const u16* gB1 = Bt + (n0 + rr + 64) * ldb + cg * 8;

    // linear LDS destinations (lane*16 within each wave's 1KB strip)
    char* lA0 = smem + w * 1024 + lane * 16;
    char* lA1 = smem + 4096 + w * 1024 + lane * 16;
    char* lB0 = smem + 8192 + w * 1024 + lane * 16;
    char* lB1 = smem + 12288 + w * 1024 + lane * 16;

    // fragment reads: row = wm*64 + mi*16 + (lane&15), chunk q = lane>>4,
    // slot = q ^ ((lane>>1)&3)
    const int fr_a = (wm << 6) + (lane & 15);
    const int fr_b = (wn << 6) + (lane & 15);
    const int sl = (lane >> 4) ^ ((lane >> 1) & 3);
    const char* pA = smem + fr_a * 64 + sl * 16;
    const char* pB = smem + 8192 + fr_b * 64 + sl * 16;

    for (int kt = 0; kt < K; kt += 32) {
        __builtin_amdgcn_global_load_lds((g_void*)(gA0 + kt), (l_void*)lA0, 16, 0, 0);
        __builtin_amdgcn_global_load_lds((g_void*)(gA1 + kt), (l_void*)lA1, 16, 0, 0);
        __builtin_amdgcn_global_load_lds((g_void*)(gB0 + kt), (l_void*)lB0, 16, 0, 0);
        __builtin_amdgcn_global_load_lds((g_void*)(gB1 + kt), (l_void*)lB1, 16, 0, 0);
        __syncthreads();
        short8 af[4], bfv[4];
#pragma unroll
        for (int i = 0; i < 4; ++i) {
            af[i]  = *(const short8*)(pA + i * 1024);
            bfv[i] = *(const short8*)(pB + i * 1024);
        }
#pragma unroll
        for (int mi = 0; mi < 4; ++mi) {
#pragma unroll
            for (int ni = 0; ni < 4; ++ni) {
                acc[mi][ni] = __builtin_amdgcn_mfma_f32_16x16x32_bf16(
                    af[mi], bfv[ni], acc[mi][ni], 0, 0, 0);
            }
        }
        __syncthreads();
    }

    // epilogue: repack 32-row strips through LDS; store bf16 or fp32 per flag
    const int out_fp32 = ofp[0];
    float* fb = (float*)smem;
    const int lrow = tid >> 3, cgp = tid & 7;
#pragma unroll 1
    for (int mi = 0; mi < 4; ++mi) {
#pragma unroll
        for (int ni = 0; ni < 4; ++ni) {
#pragma unroll
            for (int r = 0; r < 4; ++r) {
                int lr = wm * 16 + ((lane >> 4) << 2) + r;
                int lc = wn * 64 + ni * 16 + (lane & 15);
                fb[lr * 128 + lc] = acc[mi][ni][r];
            }
        }
        __syncthreads();
        int grow = (lrow < 16) ? (mi * 16 + lrow) : (48 + mi * 16 + lrow);
        const float* srcp = fb + lrow * 128 + cgp * 16;
        if (out_fp32) {
            float4* dst = (float4*)((float*)C + (size_t)(m0 + grow) * ldc + n0 + cgp * 16);
            dst[0] = make_float4(srcp[0], srcp[1], srcp[2], srcp[3]);
            dst[1] = make_float4(srcp[4], srcp[5], srcp[6], srcp[7]);
            dst[2] = make_float4(srcp[8], srcp[9], srcp[10], srcp[11]);
            dst[3] = make_float4(srcp[12], srcp[13], srcp[14], srcp[15]);
        } else {
            u32 o0 = pack2(srcp[0], srcp[1]);
            u32 o1 = pack2(srcp[2], srcp[3]);
            u32 o2 = pack2(srcp[4], srcp[5]);
            u32 o3 = pack2(srcp[6], srcp[7]);
            u32 o4 = pack2(srcp[8], srcp[9]);
            u32 o5 = pack2(srcp[10], srcp[11]);
            u32 o6 = pack2(srcp[12], srcp[13]);
            u32 o7 = pack2(srcp[14], srcp[15]);
            uint4* dst = (uint4*)((u16*)C + (size_t)(m0 + grow) * ldc + n0 + cgp * 16);
            dst[0] = make_uint4(o0, o1, o2, o3);
            dst[1] = make_uint4(o4, o5, o6, o7);
        }
        __syncthreads();
    }
}

// ---------------------------------------------------------------------------
// Transpose weights into (N,K) row-major bf16, dual-dtype source reads.
// W1T rows [0,128)=Wq^T, [128,256)=Wk^T, [256,1280)=Wv^T; OpT = o_proj^T.
// ---------------------------------------------------------------------------
__device__ __forceinline__ u16 rd_elem(const void* s, int idx, int fp32) {
    return fp32 ? f2bf(((const float*)s)[idx]) : ((const u16*)s)[idx];
}

__global__ void transpose_k(const void* __restrict__ Wq, const void* __restrict__ Wk,
                            const void* __restrict__ Wv, const void* __restrict__ Op,
                            u16* __restrict__ W1T, u16* __restrict__ OpT,
                            const int* __restrict__ flags) {
    int fp32 = flags[0];
    int id = blockIdx.x;
    const void* src; u16* dst; int Nc, mid;
    if (id < 128)       { src = Wq; dst = W1T;               Nc = 128;  mid = id; }
    else if (id < 256)  { src = Wk; dst = W1T + 128 * 1024;  Nc = 128;  mid = id - 128; }
    else if (id < 1280) { src = Wv; dst = W1T + 256 * 1024;  Nc = 1024; mid = id - 256; }
    else                { src = Op; dst = OpT;               Nc = 1024; mid = id - 1280; }
    int kt = mid & 31, nt = mid >> 5;
    __shared__ u16 tile[32][33];
    int x = threadIdx.x & 31, y0 = threadIdx.x >> 5;
#pragma unroll
    for (int yy = 0; yy < 4; ++yy) {
        int y = y0 * 4 + yy;
        tile[y][x] = rd_elem(src, (kt * 32 + y) * Nc + nt * 32 + x, fp32);
    }
    __syncthreads();
#pragma unroll
    for (int yy = 0; yy < 4; ++yy) {
        int y = y0 * 4 + yy;
        dst[(nt * 32 + y) * 1024 + kt * 32 + x] = tile[x][y];
    }
}

// ---------------------------------------------------------------------------
// Partial max of K over 256-row chunks: Pmax[b][chunk][l]
// ---------------------------------------------------------------------------
__global__ __launch_bounds__(256) void maxpart_kernel(const u16* __restrict__ QKV,
                                                      float* __restrict__ Pmax) {
    int bid = blockIdx.x;            // b*32 + chunk
    int b = bid >> 5, chunk = bid & 31;
    int tid = threadIdx.x;
    int l = tid & 127, half = tid >> 7;
    float mx = -3.0e38f;
    int t0 = chunk * 256;
    for (int i = half; i < 256; i += 2) {
        int m = b * 8192 + t0 + i;
        mx = fmaxf(mx, bf2f(QKV[(size_t)m * 1280 + 128 + l]));
    }
    __shared__ float sm[256];
    sm[tid] = mx;
    __syncthreads();
    if (tid < 128) Pmax[bid * 128 + tid] = fmaxf(sm[tid], sm[tid + 128]);
}

__global__ void maxreduce_kernel(const float* __restrict__ Pmax, float* __restrict__ Kmax) {
    int tid = threadIdx.x;           // 512: b*128 + l
    float mx = -3.0e38f;
    int b = tid >> 7;
    int l = tid & 127;
    for (int c = 0; c < 32; ++c) mx = fmaxf(mx, Pmax[(b * 32 + c) * 128 + l]);
    Kmax[tid] = mx;
}

// ---------------------------------------------------------------------------
// Partial Kv/Ksum over 256-row chunks. Block = ((b*16+h)*32 + chunk), 4 waves.
// ---------------------------------------------------------------------------
__global__ __launch_bounds__(256) void kvpart_kernel(const u16* __restrict__ QKV,
                                                     const float* __restrict__ MC,
                                                     const float* __restrict__ Kmax,
                                                     float* __restrict__ Kvp,
                                                     float* __restrict__ Ksp) {
    int bid = blockIdx.x;
    int chunk = bid & 31;
    int bh = bid >> 5;
    int h = bh & 15, b = bh >> 4;
    int w = threadIdx.x >> 6, lane = threadIdx.x & 63;

    float mx[8];
#pragma unroll
    for (int l = 0; l < 8; ++l) mx[l] = Kmax[b * 128 + h * 8 + l];

    float kv[8] = {0, 0, 0, 0, 0, 0, 0, 0};
    float ks[8] = {0, 0, 0, 0, 0, 0, 0, 0};
    int t0 = chunk * 256;
    for (int i = 0; i < 64; ++i) {
        int t = t0 + w + i * 4;
        int m = b * 8192 + t;
        const u16* row = QKV + (size_t)m * 1280;
        float v = bf2f(row[256 + h * 64 + lane]);
        uint4 kq = *(const uint4*)(row + 128 + h * 8);
        float msk = MC[b * 8192 + t];
        float vm = v * msk;
        float kf[8];
        kf[0] = __builtin_bit_cast(float, kq.x << 16);
        kf[1] = __builtin_bit_cast(float, kq.x & 0xffff0000u);
        kf[2] = __builtin_bit_cast(float, kq.y << 16);
        kf[3] = __builtin_bit_cast(float, kq.y & 0xffff0000u);
        kf[4] = __builtin_bit_cast(float, kq.z << 16);
        kf[5] = __builtin_bit_cast(float, kq.z & 0xffff0000u);
        kf[6] = __builtin_bit_cast(float, kq.w << 16);
        kf[7] = __builtin_bit_cast(float, kq.w & 0xffff0000u);
#pragma unroll
        for (int l = 0; l < 8; ++l) {
            float e = __expf(kf[l] - mx[l]) * msk;   // exp(K-max)*mask
            kv[l] += e * vm;                         // * (V*mask)
            ks[l] += e;
        }
    }
    __shared__ float red[4][8][64];
    __shared__ float redks[4][8];
#pragma unroll
    for (int l = 0; l < 8; ++l) red[w][l][lane] = kv[l];
    if (lane == 0) {
#pragma unroll
        for (int l = 0; l < 8; ++l) redks[w][l] = ks[l];
    }
    __syncthreads();
    int tid = threadIdx.x;
    for (int c = tid; c < 512; c += 256) {
        int l = c >> 6, d = c & 63;
        Kvp[bid * 512 + c] = red[0][l][d] + red[1][l][d] + red[2][l][d] + red[3][l][d];
    }
    if (tid < 8) Ksp[bid * 8 + tid] = redks[0][tid] + redks[1][tid] + redks[2][tid] + redks[3][tid];
}

__global__ void kvreduce_kernel(const float* __restrict__ Kvp, const float* __restrict__ Ksp,
                                float* __restrict__ Kv) {
    int bh = blockIdx.x;             // 64
    int tid = threadIdx.x;           // 512 = l*64+d
    int l = tid >> 6;
    float s = 0.f, ks = 0.f;
    for (int c = 0; c < 32; ++c) {
        s += Kvp[(bh * 32 + c) * 512 + tid];
        ks += Ksp[(bh * 32 + c) * 8 + l];
    }
    Kv[bh * 512 + tid] = s / ks;
}

// ---------------------------------------------------------------------------
// y[m, h*64+d] = softmax_l(Q[m,h,:]) @ Kv[b,h,l,d]; in-place over V region.
// Grid raised 256 -> 1024 blocks (32 rows/block) for 4x occupancy: the old
// 256-block launch was 1 wave/SIMD, fully latency-exposed.
// ---------------------------------------------------------------------------
__global__ __launch_bounds__(256) void y_kernel(u16* __restrict__ QKV,
                                                const float* __restrict__ Kv) {
    int bid = blockIdx.x;            // b*256 + chunk(32 rows)
    int b = bid >> 8, chunk = bid & 255;
    int w = threadIdx.x >> 6, lane = threadIdx.x & 63;
    int hh = w & 1;
    int rp = w >> 1;
    int hloc = lane >> 3;
    int h = hh * 8 + hloc;
    int dg = lane & 7;

    float4 kva[8], kvb[8];
    const float* kvp = Kv + (b * 16 + h) * 512 + dg * 8;
#pragma unroll
    for (int l = 0; l < 8; ++l) {
        kva[l] = *(const float4*)(kvp + l * 64);
        kvb[l] = *(const float4*)(kvp + l * 64 + 4);
    }
    int lgrp = lane & 56;
    for (int i = 0; i < 16; ++i) {
        int t = chunk * 32 + i * 2 + rp;
        int m = b * 8192 + t;
        u16* row = QKV + (size_t)m * 1280;
        float qv = bf2f(row[hh * 64 + lane]);
        float qm = qv;
        qm = fmaxf(qm, __shfl_xor(qm, 1));
        qm = fmaxf(qm, __shfl_xor(qm, 2));
        qm = fmaxf(qm, __shfl_xor(qm, 4));
        float e = __expf(qv - qm);
        float s = e;
        s += __shfl_xor(s, 1);
        s += __shfl_xor(s, 2);
        s += __shfl_xor(s, 4);
        float qs = e / s;
        float4 a0 = {0.f, 0.f, 0.f, 0.f}, a1 = {0.f, 0.f, 0.f, 0.f};
#pragma unroll
        for (int l = 0; l < 8; ++l) {
            float ql = __shfl(qs, lgrp + l);
            a0.x += ql * kva[l].x; a0.y += ql * kva[l].y;
            a0.z += ql * kva[l].z; a0.w += ql * kva[l].w;
            a1.x += ql * kvb[l].x; a1.y += ql * kvb[l].y;
            a1.z += ql * kvb[l].z; a1.w += ql * kvb[l].w;
        }
        uint4 o;
        o.x = pack2(a0.x, a0.y);
        o.y = pack2(a0.z, a0.w);
        o.z = pack2(a1.x, a1.y);
        o.w = pack2(a1.z, a1.w);
        *(uint4*)(row + 256 + h * 64 + dg * 8) = o;
    }
}

// ---------------------------------------------------------------------------
// Workspace layout (bytes)
// ---------------------------------------------------------------------------
#define OFF_FLAG ((size_t)0)                        // 2 ints
#define OFF_W1T  ((size_t)1024)                     // 1280*1024*2 = 2,621,440
#define OFF_OPT  ((size_t)2622464)                  // 1024*1024*2 = 2,097,152
#define OFF_PMAX ((size_t)4719616)                  // 16384*4 = 65,536
#define OFF_KMAX ((size_t)4785152)                  // 512*4 = 2,048
#define OFF_KVP  ((size_t)4787200)                  // 2048*512*4 = 4,194,304
#define OFF_KSP  ((size_t)8981504)                  // 2048*8*4 = 65,536
#define OFF_KV   ((size_t)9047040)                  // 64*512*4 = 131,072
#define OFF_MC   ((size_t)9178112)                  // 32768*4 = 131,072
#define OFF_XC   ((size_t)9309184)                  // 33554432*2 = 67,108,864
#define OFF_QKV  ((size_t)76418048)                 // 32768*1280*2 = 83,886,080
// total = 160,304,128 bytes

extern "C" void kernel_launch(void* const* d_in, const int* in_sizes, int n_in,
                              void* d_out, int out_size, void* d_ws, size_t ws_size,
                              hipStream_t stream) {
    const u16* X   = (const u16*)d_in[0];
    const void* msk = d_in[1];
    const void* Wk  = d_in[2];
    const void* Wq  = d_in[3];
    const void* Wv  = d_in[4];
    const void* Op  = d_in[5];

    char* ws = (char*)d_ws;
    int*   FLAGS = (int*)(ws + OFF_FLAG);
    u16*   W1T  = (u16*)(ws + OFF_W1T);
    u16*   OPT  = (u16*)(ws + OFF_OPT);
    float* PMAX = (float*)(ws + OFF_PMAX);
    float* KMAX = (float*)(ws + OFF_KMAX);
    float* KVP  = (float*)(ws + OFF_KVP);
    float* KSP  = (float*)(ws + OFF_KSP);
    float* KV   = (float*)(ws + OFF_KV);
    float* MC   = (float*)(ws + OFF_MC);
    u16*   XC   = (u16*)(ws + OFF_XC);
    u16*   QKV  = (u16*)(ws + OFF_QKV);

    // 0) detect input dtype (flags[0]=1 -> fp32), flags[1]=0 always
    detect_kernel<<<1, 256, 0, stream>>>(X, FLAGS);
    // 0b) canonicalize X (no-op if bf16) and mask (always fp32 canonical)
    convert_x<<<16384, 256, 0, stream>>>((const float*)d_in[0], XC, FLAGS, 33554432);
    convert_mask<<<128, 256, 0, stream>>>(msk, MC, FLAGS, 32768);
    // 1) transpose weights to (N,K) bf16 (dual-dtype reads)
    transpose_k<<<2304, 256, 0, stream>>>(Wq, Wk, Wv, Op, W1T, OPT, FLAGS);
    // 2) fused QKV projection: QKV[m,0:128)=Q, [128:256)=K, [256:1280)=V
    gemm_bt<<<2560, 256, 0, stream>>>(X, XC, 1024, W1T, 1024, QKV, 1280, 256, 1024,
                                      FLAGS, FLAGS + 1);
    // 3) global max of K over T
    maxpart_kernel<<<128, 256, 0, stream>>>(QKV, PMAX);
    maxreduce_kernel<<<1, 512, 0, stream>>>(PMAX, KMAX);
    // 4) Kv state + Ksum
    kvpart_kernel<<<2048, 256, 0, stream>>>(QKV, MC, KMAX, KVP, KSP);
    kvreduce_kernel<<<64, 512, 0, stream>>>(KVP, KSP, KV);
    // 5) y = softmax(Q) @ Kv, in-place over V region
    y_kernel<<<1024, 256, 0, stream>>>(QKV, KV);
    // 6) out = y @ o_proj (output dtype per detected flag)
    gemm_bt<<<2048, 256, 0, stream>>>(QKV + 256, QKV + 256, 1280, OPT, 1024,
                                      d_out, 1024, 256, 1024, FLAGS + 1, FLAGS);
}

// Round 5
// 617.028 us; speedup vs baseline: 5.8812x; 5.8812x over previous
//
#include <hip/hip_runtime.h>
#include <hip/hip_bf16.h>

typedef unsigned short u16;
typedef unsigned int   u32;

typedef __attribute__((ext_vector_type(8))) short short8;
typedef __attribute__((ext_vector_type(4))) float f32x4;

typedef const __attribute__((address_space(1))) void g_void;
typedef __attribute__((address_space(3))) void l_void;

__device__ __forceinline__ float bf2f(u16 u) {
    u32 x = ((u32)u) << 16;
    return __builtin_bit_cast(float, x);
}
__device__ __forceinline__ u16 f2bf(float f) {
    u32 u = __builtin_bit_cast(u32, f);
    u32 r = (u + 0x7FFFu + ((u >> 16) & 1u)) >> 16;
    return (u16)r;
}
__device__ __forceinline__ u32 pack2(float a, float b) {
    return (u32)f2bf(a) | ((u32)f2bf(b) << 16);
}

// ---------------------------------------------------------------------------
// Dtype detector: reads first 16384 u16 words of X. bf16 data -> ~100% sane
// exponent fields; fp32 data reinterpreted as u16 -> ~57%. flags[0]=1 => fp32.
// flags[1] is a guaranteed-zero word used by consumers needing "always bf16".
// ---------------------------------------------------------------------------
__global__ void detect_kernel(const u16* __restrict__ X, int* __restrict__ flags) {
    __shared__ int cnt[256];
    int c = 0;
    for (int i = threadIdx.x; i < 16384; i += 256) {
        u16 v = X[i];
        int e = (v >> 7) & 0xFF;
        c += (e >= 104 && e <= 140) ? 1 : 0;
    }
    cnt[threadIdx.x] = c;
    __syncthreads();
    for (int s = 128; s > 0; s >>= 1) {
        if (threadIdx.x < s) cnt[threadIdx.x] += cnt[threadIdx.x + s];
        __syncthreads();
    }
    if (threadIdx.x == 0) {
        flags[0] = (cnt[0] < 14746) ? 1 : 0;   // <90% sane => fp32
        flags[1] = 0;
    }
}

// X canonicalization: only does work when input is fp32 (copies to bf16 XC).
__global__ __launch_bounds__(256) void convert_x(const float* __restrict__ Xf,
                                                 u16* __restrict__ XC,
                                                 const int* __restrict__ flags, int n) {
    if (flags[0] == 0) return;
    int i = (blockIdx.x * 256 + threadIdx.x) * 8;
    if (i >= n) return;
    float4 a = *(const float4*)(Xf + i);
    float4 b = *(const float4*)(Xf + i + 4);
    uint4 o;
    o.x = pack2(a.x, a.y); o.y = pack2(a.z, a.w);
    o.z = pack2(b.x, b.y); o.w = pack2(b.z, b.w);
    *(uint4*)(XC + i) = o;
}

// mask canonicalization to fp32 (always runs; tiny).
__global__ void convert_mask(const void* __restrict__ m, float* __restrict__ MC,
                             const int* __restrict__ flags, int n) {
    int i = blockIdx.x * 256 + threadIdx.x;
    if (i >= n) return;
    MC[i] = flags[0] ? ((const float*)m)[i] : bf2f(((const u16*)m)[i]);
}

// ---------------------------------------------------------------------------
// GEMM: C(MxN, ldc) = A(MxK, bf16, lda) * Bt(NxK, bf16, ldb)^T
// 128x128 tile, BK=32, 4 waves (2x2), 16x16x32 bf16 MFMA.
// Staging via global_load_lds width=16 (linear LDS dest, swizzled global src).
// EPILOGUE IS FULLY UNROLLED: the previous `#pragma unroll 1` on the mi loop
// made acc[mi][..] runtime-indexed -> the whole accumulator array was
// allocated in SCRATCH for the entire kernel (rule #20), turning the main
// K-loop into a scratch-bandwidth benchmark (MfmaUtil 1.9%, 8.9 GB HBM/disp).
// A chosen between A0/A1 by aselp[0]; C stored bf16 or fp32 per ofp[0].
// ---------------------------------------------------------------------------
__global__ __launch_bounds__(256) void gemm_bt(
    const u16* __restrict__ A0, const u16* __restrict__ A1, int lda,
    const u16* __restrict__ Bt, int ldb,
    void* __restrict__ C, int ldc,
    int Mtiles, int K,
    const int* __restrict__ aselp, const int* __restrict__ ofp) {
    __shared__ char smem[16384];

    const u16* A = aselp[0] ? A1 : A0;

    const int tid = threadIdx.x;
    const int w = tid >> 6, lane = tid & 63;
    const int mt = blockIdx.x % Mtiles;
    const int nt = blockIdx.x / Mtiles;
    const int m0 = mt << 7, n0 = nt << 7;
    const int wm = w >> 1, wn = w & 1;

    f32x4 acc[4][4] = {};

    // staging: row rr = w*16 + lane/4 (plus +64 for second store),
    // LDS slot s = lane&3 holds global chunk cg = s ^ swz(row), swz(r)=(r>>1)&3
    const int rr = w * 16 + (lane >> 2);
    const int cg = (lane & 3) ^ ((lane >> 3) & 3);

    const u16* gA0 = A + (m0 + rr) * lda + cg * 8;
    const u16* gA1 = A + (m0 + rr + 64) * lda + cg * 8;
    const u16* gB0 = Bt + (n0 + rr) * ldb + cg * 8;
    const u16* gB1 = Bt + (n0 + rr + 64) * ldb + cg * 8;

    // linear LDS destinations (lane*16 within each wave's 1KB strip)
    char* lA0 = smem + w * 1024 + lane * 16;
    char* lA1 = smem + 4096 + w * 1024 + lane * 16;
    char* lB0 = smem + 8192 + w * 1024 + lane * 16;
    char* lB1 = smem + 12288 + w * 1024 + lane * 16;

    // fragment reads: row = wm*64 + mi*16 + (lane&15), chunk q = lane>>4,
    // slot = q ^ ((lane>>1)&3)
    const int fr_a = (wm << 6) + (lane & 15);
    const int fr_b = (wn << 6) + (lane & 15);
    const int sl = (lane >> 4) ^ ((lane >> 1) & 3);
    const char* pA = smem + fr_a * 64 + sl * 16;
    const char* pB = smem + 8192 + fr_b * 64 + sl * 16;

    for (int kt = 0; kt < K; kt += 32) {
        __builtin_amdgcn_global_load_lds((g_void*)(gA0 + kt), (l_void*)lA0, 16, 0, 0);
        __builtin_amdgcn_global_load_lds((g_void*)(gA1 + kt), (l_void*)lA1, 16, 0, 0);
        __builtin_amdgcn_global_load_lds((g_void*)(gB0 + kt), (l_void*)lB0, 16, 0, 0);
        __builtin_amdgcn_global_load_lds((g_void*)(gB1 + kt), (l_void*)lB1, 16, 0, 0);
        __syncthreads();
        short8 af[4], bfv[4];
#pragma unroll
        for (int i = 0; i < 4; ++i) {
            af[i]  = *(const short8*)(pA + i * 1024);
            bfv[i] = *(const short8*)(pB + i * 1024);
        }
#pragma unroll
        for (int mi = 0; mi < 4; ++mi) {
#pragma unroll
            for (int ni = 0; ni < 4; ++ni) {
                acc[mi][ni] = __builtin_amdgcn_mfma_f32_16x16x32_bf16(
                    af[mi], bfv[ni], acc[mi][ni], 0, 0, 0);
            }
        }
        __syncthreads();
    }

    // epilogue: repack 32-row strips through LDS; store bf16 or fp32 per flag.
    // FULLY unrolled so every acc index is compile-time constant (rule #20).
    const int out_fp32 = ofp[0];
    float* fb = (float*)smem;
    const int lrow = tid >> 3, cgp = tid & 7;
#pragma unroll
    for (int mi = 0; mi < 4; ++mi) {
#pragma unroll
        for (int ni = 0; ni < 4; ++ni) {
#pragma unroll
            for (int r = 0; r < 4; ++r) {
                int lr = wm * 16 + ((lane >> 4) << 2) + r;
                int lc = wn * 64 + ni * 16 + (lane & 15);
                fb[lr * 128 + lc] = acc[mi][ni][r];
            }
        }
        __syncthreads();
        int grow = (lrow < 16) ? (mi * 16 + lrow) : (48 + mi * 16 + lrow);
        const float* srcp = fb + lrow * 128 + cgp * 16;
        if (out_fp32) {
            float4* dst = (float4*)((float*)C + (size_t)(m0 + grow) * ldc + n0 + cgp * 16);
            dst[0] = make_float4(srcp[0], srcp[1], srcp[2], srcp[3]);
            dst[1] = make_float4(srcp[4], srcp[5], srcp[6], srcp[7]);
            dst[2] = make_float4(srcp[8], srcp[9], srcp[10], srcp[11]);
            dst[3] = make_float4(srcp[12], srcp[13], srcp[14], srcp[15]);
        } else {
            u32 o0 = pack2(srcp[0], srcp[1]);
            u32 o1 = pack2(srcp[2], srcp[3]);
            u32 o2 = pack2(srcp[4], srcp[5]);
            u32 o3 = pack2(srcp[6], srcp[7]);
            u32 o4 = pack2(srcp[8], srcp[9]);
            u32 o5 = pack2(srcp[10], srcp[11]);
            u32 o6 = pack2(srcp[12], srcp[13]);
            u32 o7 = pack2(srcp[14], srcp[15]);
            uint4* dst = (uint4*)((u16*)C + (size_t)(m0 + grow) * ldc + n0 + cgp * 16);
            dst[0] = make_uint4(o0, o1, o2, o3);
            dst[1] = make_uint4(o4, o5, o6, o7);
        }
        __syncthreads();
    }
}

// ---------------------------------------------------------------------------
// Transpose weights into (N,K) row-major bf16, dual-dtype source reads.
// W1T rows [0,128)=Wq^T, [128,256)=Wk^T, [256,1280)=Wv^T; OpT = o_proj^T.
// ---------------------------------------------------------------------------
__device__ __forceinline__ u16 rd_elem(const void* s, int idx, int fp32) {
    return fp32 ? f2bf(((const float*)s)[idx]) : ((const u16*)s)[idx];
}

__global__ void transpose_k(const void* __restrict__ Wq, const void* __restrict__ Wk,
                            const void* __restrict__ Wv, const void* __restrict__ Op,
                            u16* __restrict__ W1T, u16* __restrict__ OpT,
                            const int* __restrict__ flags) {
    int fp32 = flags[0];
    int id = blockIdx.x;
    const void* src; u16* dst; int Nc, mid;
    if (id < 128)       { src = Wq; dst = W1T;               Nc = 128;  mid = id; }
    else if (id < 256)  { src = Wk; dst = W1T + 128 * 1024;  Nc = 128;  mid = id - 128; }
    else if (id < 1280) { src = Wv; dst = W1T + 256 * 1024;  Nc = 1024; mid = id - 256; }
    else                { src = Op; dst = OpT;               Nc = 1024; mid = id - 1280; }
    int kt = mid & 31, nt = mid >> 5;
    __shared__ u16 tile[32][33];
    int x = threadIdx.x & 31, y0 = threadIdx.x >> 5;
#pragma unroll
    for (int yy = 0; yy < 4; ++yy) {
        int y = y0 * 4 + yy;
        tile[y][x] = rd_elem(src, (kt * 32 + y) * Nc + nt * 32 + x, fp32);
    }
    __syncthreads();
#pragma unroll
    for (int yy = 0; yy < 4; ++yy) {
        int y = y0 * 4 + yy;
        dst[(nt * 32 + y) * 1024 + kt * 32 + x] = tile[x][y];
    }
}

// ---------------------------------------------------------------------------
// Partial max of K over 256-row chunks: Pmax[b][chunk][l]
// ---------------------------------------------------------------------------
__global__ __launch_bounds__(256) void maxpart_kernel(const u16* __restrict__ QKV,
                                                      float* __restrict__ Pmax) {
    int bid = blockIdx.x;            // b*32 + chunk
    int b = bid >> 5, chunk = bid & 31;
    int tid = threadIdx.x;
    int l = tid & 127, half = tid >> 7;
    float mx = -3.0e38f;
    int t0 = chunk * 256;
    for (int i = half; i < 256; i += 2) {
        int m = b * 8192 + t0 + i;
        mx = fmaxf(mx, bf2f(QKV[(size_t)m * 1280 + 128 + l]));
    }
    __shared__ float sm[256];
    sm[tid] = mx;
    __syncthreads();
    if (tid < 128) Pmax[bid * 128 + tid] = fmaxf(sm[tid], sm[tid + 128]);
}

__global__ void maxreduce_kernel(const float* __restrict__ Pmax, float* __restrict__ Kmax) {
    int tid = threadIdx.x;           // 512: b*128 + l
    float mx = -3.0e38f;
    int b = tid >> 7;
    int l = tid & 127;
    for (int c = 0; c < 32; ++c) mx = fmaxf(mx, Pmax[(b * 32 + c) * 128 + l]);
    Kmax[tid] = mx;
}

// ---------------------------------------------------------------------------
// Partial Kv/Ksum over 256-row chunks. Block = ((b*16+h)*32 + chunk), 4 waves.
// ---------------------------------------------------------------------------
__global__ __launch_bounds__(256) void kvpart_kernel(const u16* __restrict__ QKV,
                                                     const float* __restrict__ MC,
                                                     const float* __restrict__ Kmax,
                                                     float* __restrict__ Kvp,
                                                     float* __restrict__ Ksp) {
    int bid = blockIdx.x;
    int chunk = bid & 31;
    int bh = bid >> 5;
    int h = bh & 15, b = bh >> 4;
    int w = threadIdx.x >> 6, lane = threadIdx.x & 63;

    float mx[8];
#pragma unroll
    for (int l = 0; l < 8; ++l) mx[l] = Kmax[b * 128 + h * 8 + l];

    float kv[8] = {0, 0, 0, 0, 0, 0, 0, 0};
    float ks[8] = {0, 0, 0, 0, 0, 0, 0, 0};
    int t0 = chunk * 256;
    for (int i = 0; i < 64; ++i) {
        int t = t0 + w + i * 4;
        int m = b * 8192 + t;
        const u16* row = QKV + (size_t)m * 1280;
        float v = bf2f(row[256 + h * 64 + lane]);
        uint4 kq = *(const uint4*)(row + 128 + h * 8);
        float msk = MC[b * 8192 + t];
        float vm = v * msk;
        float kf[8];
        kf[0] = __builtin_bit_cast(float, kq.x << 16);
        kf[1] = __builtin_bit_cast(float, kq.x & 0xffff0000u);
        kf[2] = __builtin_bit_cast(float, kq.y << 16);
        kf[3] = __builtin_bit_cast(float, kq.y & 0xffff0000u);
        kf[4] = __builtin_bit_cast(float, kq.z << 16);
        kf[5] = __builtin_bit_cast(float, kq.z & 0xffff0000u);
        kf[6] = __builtin_bit_cast(float, kq.w << 16);
        kf[7] = __builtin_bit_cast(float, kq.w & 0xffff0000u);
#pragma unroll
        for (int l = 0; l < 8; ++l) {
            float e = __expf(kf[l] - mx[l]) * msk;   // exp(K-max)*mask
            kv[l] += e * vm;                         // * (V*mask)
            ks[l] += e;
        }
    }
    __shared__ float red[4][8][64];
    __shared__ float redks[4][8];
#pragma unroll
    for (int l = 0; l < 8; ++l) red[w][l][lane] = kv[l];
    if (lane == 0) {
#pragma unroll
        for (int l = 0; l < 8; ++l) redks[w][l] = ks[l];
    }
    __syncthreads();
    int tid = threadIdx.x;
    for (int c = tid; c < 512; c += 256) {
        int l = c >> 6, d = c & 63;
        Kvp[bid * 512 + c] = red[0][l][d] + red[1][l][d] + red[2][l][d] + red[3][l][d];
    }
    if (tid < 8) Ksp[bid * 8 + tid] = redks[0][tid] + redks[1][tid] + redks[2][tid] + redks[3][tid];
}

__global__ void kvreduce_kernel(const float* __restrict__ Kvp, const float* __restrict__ Ksp,
                                float* __restrict__ Kv) {
    int bh = blockIdx.x;             // 64
    int tid = threadIdx.x;           // 512 = l*64+d
    int l = tid >> 6;
    float s = 0.f, ks = 0.f;
    for (int c = 0; c < 32; ++c) {
        s += Kvp[(bh * 32 + c) * 512 + tid];
        ks += Ksp[(bh * 32 + c) * 8 + l];
    }
    Kv[bh * 512 + tid] = s / ks;
}

// ---------------------------------------------------------------------------
// y[m, h*64+d] = softmax_l(Q[m,h,:]) @ Kv[b,h,l,d]; in-place over V region.
// 1024 blocks (32 rows/block) for 4x occupancy vs the original 256.
// ---------------------------------------------------------------------------
__global__ __launch_bounds__(256) void y_kernel(u16* __restrict__ QKV,
                                                const float* __restrict__ Kv) {
    int bid = blockIdx.x;            // b*256 + chunk(32 rows)
    int b = bid >> 8, chunk = bid & 255;
    int w = threadIdx.x >> 6, lane = threadIdx.x & 63;
    int hh = w & 1;
    int rp = w >> 1;
    int hloc = lane >> 3;
    int h = hh * 8 + hloc;
    int dg = lane & 7;

    float4 kva[8], kvb[8];
    const float* kvp = Kv + (b * 16 + h) * 512 + dg * 8;
#pragma unroll
    for (int l = 0; l < 8; ++l) {
        kva[l] = *(const float4*)(kvp + l * 64);
        kvb[l] = *(const float4*)(kvp + l * 64 + 4);
    }
    int lgrp = lane & 56;
    for (int i = 0; i < 16; ++i) {
        int t = chunk * 32 + i * 2 + rp;
        int m = b * 8192 + t;
        u16* row = QKV + (size_t)m * 1280;
        float qv = bf2f(row[hh * 64 + lane]);
        float qm = qv;
        qm = fmaxf(qm, __shfl_xor(qm, 1));
        qm = fmaxf(qm, __shfl_xor(qm, 2));
        qm = fmaxf(qm, __shfl_xor(qm, 4));
        float e = __expf(qv - qm);
        float s = e;
        s += __shfl_xor(s, 1);
        s += __shfl_xor(s, 2);
        s += __shfl_xor(s, 4);
        float qs = e / s;
        float4 a0 = {0.f, 0.f, 0.f, 0.f}, a1 = {0.f, 0.f, 0.f, 0.f};
#pragma unroll
        for (int l = 0; l < 8; ++l) {
            float ql = __shfl(qs, lgrp + l);
            a0.x += ql * kva[l].x; a0.y += ql * kva[l].y;
            a0.z += ql * kva[l].z; a0.w += ql * kva[l].w;
            a1.x += ql * kvb[l].x; a1.y += ql * kvb[l].y;
            a1.z += ql * kvb[l].z; a1.w += ql * kvb[l].w;
        }
        uint4 o;
        o.x = pack2(a0.x, a0.y);
        o.y = pack2(a0.z, a0.w);
        o.z = pack2(a1.x, a1.y);
        o.w = pack2(a1.z, a1.w);
        *(uint4*)(row + 256 + h * 64 + dg * 8) = o;
    }
}

// ---------------------------------------------------------------------------
// Workspace layout (bytes)
// ---------------------------------------------------------------------------
#define OFF_FLAG ((size_t)0)                        // 2 ints
#define OFF_W1T  ((size_t)1024)                     // 1280*1024*2 = 2,621,440
#define OFF_OPT  ((size_t)2622464)                  // 1024*1024*2 = 2,097,152
#define OFF_PMAX ((size_t)4719616)                  // 16384*4 = 65,536
#define OFF_KMAX ((size_t)4785152)                  // 512*4 = 2,048
#define OFF_KVP  ((size_t)4787200)                  // 2048*512*4 = 4,194,304
#define OFF_KSP  ((size_t)8981504)                  // 2048*8*4 = 65,536
#define OFF_KV   ((size_t)9047040)                  // 64*512*4 = 131,072
#define OFF_MC   ((size_t)9178112)                  // 32768*4 = 131,072
#define OFF_XC   ((size_t)9309184)                  // 33554432*2 = 67,108,864
#define OFF_QKV  ((size_t)76418048)                 // 32768*1280*2 = 83,886,080
// total = 160,304,128 bytes

extern "C" void kernel_launch(void* const* d_in, const int* in_sizes, int n_in,
                              void* d_out, int out_size, void* d_ws, size_t ws_size,
                              hipStream_t stream) {
    const u16* X   = (const u16*)d_in[0];
    const void* msk = d_in[1];
    const void* Wk  = d_in[2];
    const void* Wq  = d_in[3];
    const void* Wv  = d_in[4];
    const void* Op  = d_in[5];

    char* ws = (char*)d_ws;
    int*   FLAGS = (int*)(ws + OFF_FLAG);
    u16*   W1T  = (u16*)(ws + OFF_W1T);
    u16*   OPT  = (u16*)(ws + OFF_OPT);
    float* PMAX = (float*)(ws + OFF_PMAX);
    float* KMAX = (float*)(ws + OFF_KMAX);
    float* KVP  = (float*)(ws + OFF_KVP);
    float* KSP  = (float*)(ws + OFF_KSP);
    float* KV   = (float*)(ws + OFF_KV);
    float* MC   = (float*)(ws + OFF_MC);
    u16*   XC   = (u16*)(ws + OFF_XC);
    u16*   QKV  = (u16*)(ws + OFF_QKV);

    // 0) detect input dtype (flags[0]=1 -> fp32), flags[1]=0 always
    detect_kernel<<<1, 256, 0, stream>>>(X, FLAGS);
    // 0b) canonicalize X (no-op if bf16) and mask (always fp32 canonical)
    convert_x<<<16384, 256, 0, stream>>>((const float*)d_in[0], XC, FLAGS, 33554432);
    convert_mask<<<128, 256, 0, stream>>>(msk, MC, FLAGS, 32768);
    // 1) transpose weights to (N,K) bf16 (dual-dtype reads)
    transpose_k<<<2304, 256, 0, stream>>>(Wq, Wk, Wv, Op, W1T, OPT, FLAGS);
    // 2) fused QKV projection: QKV[m,0:128)=Q, [128:256)=K, [256:1280)=V
    gemm_bt<<<2560, 256, 0, stream>>>(X, XC, 1024, W1T, 1024, QKV, 1280, 256, 1024,
                                      FLAGS, FLAGS + 1);
    // 3) global max of K over T
    maxpart_kernel<<<128, 256, 0, stream>>>(QKV, PMAX);
    maxreduce_kernel<<<1, 512, 0, stream>>>(PMAX, KMAX);
    // 4) Kv state + Ksum
    kvpart_kernel<<<2048, 256, 0, stream>>>(QKV, MC, KMAX, KVP, KSP);
    kvreduce_kernel<<<64, 512, 0, stream>>>(KVP, KSP, KV);
    // 5) y = softmax(Q) @ Kv, in-place over V region
    y_kernel<<<1024, 256, 0, stream>>>(QKV, KV);
    // 6) out = y @ o_proj (output dtype per detected flag)
    gemm_bt<<<2048, 256, 0, stream>>>(QKV + 256, QKV + 256, 1280, OPT, 1024,
                                      d_out, 1024, 256, 1024, FLAGS + 1, FLAGS);
}

// Round 8
// 601.866 us; speedup vs baseline: 6.0294x; 1.0252x over previous
//
#include <hip/hip_runtime.h>
#include <hip/hip_bf16.h>

typedef unsigned short u16;
typedef unsigned int   u32;

typedef __attribute__((ext_vector_type(8))) short short8;
typedef __attribute__((ext_vector_type(4))) float f32x4;

typedef const __attribute__((address_space(1))) void g_void;
typedef __attribute__((address_space(3))) void l_void;

__device__ __forceinline__ float bf2f(u16 u) {
    u32 x = ((u32)u) << 16;
    return __builtin_bit_cast(float, x);
}
__device__ __forceinline__ u16 f2bf(float f) {
    u32 u = __builtin_bit_cast(u32, f);
    u32 r = (u + 0x7FFFu + ((u >> 16) & 1u)) >> 16;
    return (u16)r;
}
__device__ __forceinline__ u32 pack2(float a, float b) {
    return (u32)f2bf(a) | ((u32)f2bf(b) << 16);
}

// ---------------------------------------------------------------------------
// Dtype detector: reads first 16384 u16 words of X. bf16 data -> ~100% sane
// exponent fields; fp32 data reinterpreted as u16 -> ~57%. flags[0]=1 => fp32.
// flags[1] is a guaranteed-zero word used by consumers needing "always bf16".
// ---------------------------------------------------------------------------
__global__ void detect_kernel(const u16* __restrict__ X, int* __restrict__ flags) {
    __shared__ int cnt[256];
    int c = 0;
    for (int i = threadIdx.x; i < 16384; i += 256) {
        u16 v = X[i];
        int e = (v >> 7) & 0xFF;
        c += (e >= 104 && e <= 140) ? 1 : 0;
    }
    cnt[threadIdx.x] = c;
    __syncthreads();
    for (int s = 128; s > 0; s >>= 1) {
        if (threadIdx.x < s) cnt[threadIdx.x] += cnt[threadIdx.x + s];
        __syncthreads();
    }
    if (threadIdx.x == 0) {
        flags[0] = (cnt[0] < 14746) ? 1 : 0;   // <90% sane => fp32
        flags[1] = 0;
    }
}

// X canonicalization: only does work when input is fp32 (copies to bf16 XC).
__global__ __launch_bounds__(256) void convert_x(const float* __restrict__ Xf,
                                                 u16* __restrict__ XC,
                                                 const int* __restrict__ flags, int n) {
    if (flags[0] == 0) return;
    int i = (blockIdx.x * 256 + threadIdx.x) * 8;
    if (i >= n) return;
    float4 a = *(const float4*)(Xf + i);
    float4 b = *(const float4*)(Xf + i + 4);
    uint4 o;
    o.x = pack2(a.x, a.y); o.y = pack2(a.z, a.w);
    o.z = pack2(b.x, b.y); o.w = pack2(b.z, b.w);
    *(uint4*)(XC + i) = o;
}

// mask canonicalization to fp32 (always runs; tiny).
__global__ void convert_mask(const void* __restrict__ m, float* __restrict__ MC,
                             const int* __restrict__ flags, int n) {
    int i = blockIdx.x * 256 + threadIdx.x;
    if (i >= n) return;
    MC[i] = flags[0] ? ((const float*)m)[i] : bf2f(((const u16*)m)[i]);
}

// ---------------------------------------------------------------------------
// GEMM: C(MxN, ldc) = A(MxK, bf16, lda) * Bt(NxK, bf16, ldb)^T
// 128x128 tile, BK=32, 4 waves (2x2), 16x16x32 bf16 MFMA.
// Round-5 changes:
//  * mt = bid / Ntiles (A-panel readers now CONSECUTIVE in dispatch order ->
//    panel served from L2/L3 once instead of re-fetched; FETCH was 250 MB vs
//    ideal ~155 MB).
//  * epilogue repack stride 128 -> 132 floats: old stride put all 64 lanes'
//    float4 reads on banks {0-3,16-19} = 8-way conflict (3.28M/dispatch);
//    +4 pad spreads lrow across banks -> ~4-way.
// ---------------------------------------------------------------------------
__global__ __launch_bounds__(256) void gemm_bt(
    const u16* __restrict__ A0, const u16* __restrict__ A1, int lda,
    const u16* __restrict__ Bt, int ldb,
    void* __restrict__ C, int ldc,
    int Mtiles, int K,
    const int* __restrict__ aselp, const int* __restrict__ ofp) {
    __shared__ char smem[17408];

    const u16* A = aselp[0] ? A1 : A0;

    const int tid = threadIdx.x;
    const int w = tid >> 6, lane = tid & 63;
    const int Ntiles = gridDim.x / Mtiles;
    const int mt = blockIdx.x / Ntiles;
    const int nt = blockIdx.x % Ntiles;
    const int m0 = mt << 7, n0 = nt << 7;
    const int wm = w >> 1, wn = w & 1;

    f32x4 acc[4][4] = {};

    // staging: row rr = w*16 + lane/4 (plus +64 for second store),
    // LDS slot s = lane&3 holds global chunk cg = s ^ swz(row), swz(r)=(r>>1)&3
    const int rr = w * 16 + (lane >> 2);
    const int cg = (lane & 3) ^ ((lane >> 3) & 3);

    const u16* gA0 = A + (m0 + rr) * lda + cg * 8;
    const u16* gA1 = A + (m0 + rr + 64) * lda + cg * 8;
    const u16* gB0 = Bt + (n0 + rr) * ldb + cg * 8;
    const u16* gB1 = Bt + (n0 + rr + 64) * ldb + cg * 8;

    // linear LDS destinations (lane*16 within each wave's 1KB strip)
    char* lA0 = smem + w * 1024 + lane * 16;
    char* lA1 = smem + 4096 + w * 1024 + lane * 16;
    char* lB0 = smem + 8192 + w * 1024 + lane * 16;
    char* lB1 = smem + 12288 + w * 1024 + lane * 16;

    // fragment reads: row = wm*64 + mi*16 + (lane&15), chunk q = lane>>4,
    // slot = q ^ ((lane>>1)&3)
    const int fr_a = (wm << 6) + (lane & 15);
    const int fr_b = (wn << 6) + (lane & 15);
    const int sl = (lane >> 4) ^ ((lane >> 1) & 3);
    const char* pA = smem + fr_a * 64 + sl * 16;
    const char* pB = smem + 8192 + fr_b * 64 + sl * 16;

    for (int kt = 0; kt < K; kt += 32) {
        __builtin_amdgcn_global_load_lds((g_void*)(gA0 + kt), (l_void*)lA0, 16, 0, 0);
        __builtin_amdgcn_global_load_lds((g_void*)(gA1 + kt), (l_void*)lA1, 16, 0, 0);
        __builtin_amdgcn_global_load_lds((g_void*)(gB0 + kt), (l_void*)lB0, 16, 0, 0);
        __builtin_amdgcn_global_load_lds((g_void*)(gB1 + kt), (l_void*)lB1, 16, 0, 0);
        __syncthreads();
        short8 af[4], bfv[4];
#pragma unroll
        for (int i = 0; i < 4; ++i) {
            af[i]  = *(const short8*)(pA + i * 1024);
            bfv[i] = *(const short8*)(pB + i * 1024);
        }
#pragma unroll
        for (int mi = 0; mi < 4; ++mi) {
#pragma unroll
            for (int ni = 0; ni < 4; ++ni) {
                acc[mi][ni] = __builtin_amdgcn_mfma_f32_16x16x32_bf16(
                    af[mi], bfv[ni], acc[mi][ni], 0, 0, 0);
            }
        }
        __syncthreads();
    }

    // epilogue: repack 32-row strips through LDS (stride 132 = bank pad);
    // fully unrolled so every acc index is compile-time constant (rule #20).
    const int out_fp32 = ofp[0];
    float* fb = (float*)smem;
    const int lrow = tid >> 3, cgp = tid & 7;
#pragma unroll
    for (int mi = 0; mi < 4; ++mi) {
#pragma unroll
        for (int ni = 0; ni < 4; ++ni) {
#pragma unroll
            for (int r = 0; r < 4; ++r) {
                int lr = wm * 16 + ((lane >> 4) << 2) + r;
                int lc = wn * 64 + ni * 16 + (lane & 15);
                fb[lr * 132 + lc] = acc[mi][ni][r];
            }
        }
        __syncthreads();
        int grow = (lrow < 16) ? (mi * 16 + lrow) : (48 + mi * 16 + lrow);
        const float* srcp = fb + lrow * 132 + cgp * 16;
        if (out_fp32) {
            float4* dst = (float4*)((float*)C + (size_t)(m0 + grow) * ldc + n0 + cgp * 16);
            dst[0] = make_float4(srcp[0], srcp[1], srcp[2], srcp[3]);
            dst[1] = make_float4(srcp[4], srcp[5], srcp[6], srcp[7]);
            dst[2] = make_float4(srcp[8], srcp[9], srcp[10], srcp[11]);
            dst[3] = make_float4(srcp[12], srcp[13], srcp[14], srcp[15]);
        } else {
            u32 o0 = pack2(srcp[0], srcp[1]);
            u32 o1 = pack2(srcp[2], srcp[3]);
            u32 o2 = pack2(srcp[4], srcp[5]);
            u32 o3 = pack2(srcp[6], srcp[7]);
            u32 o4 = pack2(srcp[8], srcp[9]);
            u32 o5 = pack2(srcp[10], srcp[11]);
            u32 o6 = pack2(srcp[12], srcp[13]);
            u32 o7 = pack2(srcp[14], srcp[15]);
            uint4* dst = (uint4*)((u16*)C + (size_t)(m0 + grow) * ldc + n0 + cgp * 16);
            dst[0] = make_uint4(o0, o1, o2, o3);
            dst[1] = make_uint4(o4, o5, o6, o7);
        }
        __syncthreads();
    }
}

// ---------------------------------------------------------------------------
// Transpose weights into (N,K) row-major bf16, dual-dtype source reads.
// W1T rows [0,128)=Wq^T, [128,256)=Wk^T, [256,1280)=Wv^T; OpT = o_proj^T.
// ---------------------------------------------------------------------------
__device__ __forceinline__ u16 rd_elem(const void* s, int idx, int fp32) {
    return fp32 ? f2bf(((const float*)s)[idx]) : ((const u16*)s)[idx];
}

__global__ void transpose_k(const void* __restrict__ Wq, const void* __restrict__ Wk,
                            const void* __restrict__ Wv, const void* __restrict__ Op,
                            u16* __restrict__ W1T, u16* __restrict__ OpT,
                            const int* __restrict__ flags) {
    int fp32 = flags[0];
    int id = blockIdx.x;
    const void* src; u16* dst; int Nc, mid;
    if (id < 128)       { src = Wq; dst = W1T;               Nc = 128;  mid = id; }
    else if (id < 256)  { src = Wk; dst = W1T + 128 * 1024;  Nc = 128;  mid = id - 128; }
    else if (id < 1280) { src = Wv; dst = W1T + 256 * 1024;  Nc = 1024; mid = id - 256; }
    else                { src = Op; dst = OpT;               Nc = 1024; mid = id - 1280; }
    int kt = mid & 31, nt = mid >> 5;
    __shared__ u16 tile[32][33];
    int x = threadIdx.x & 31, y0 = threadIdx.x >> 5;
#pragma unroll
    for (int yy = 0; yy < 4; ++yy) {
        int y = y0 * 4 + yy;
        tile[y][x] = rd_elem(src, (kt * 32 + y) * Nc + nt * 32 + x, fp32);
    }
    __syncthreads();
#pragma unroll
    for (int yy = 0; yy < 4; ++yy) {
        int y = y0 * 4 + yy;
        dst[(nt * 32 + y) * 1024 + kt * 32 + x] = tile[x][y];
    }
}

// ---------------------------------------------------------------------------
// Partial max of K over 64-row chunks: Pmax[b*128+chunk][128].
// Redesign: 512 blocks (was 128 -> 0.5 block/CU latency-bound), uint4 loads
// (16 B/lane coalesced, was scalar 2 B strided).
// ---------------------------------------------------------------------------
__global__ __launch_bounds__(256) void maxpart_kernel(const u16* __restrict__ QKV,
                                                      float* __restrict__ Pmax) {
    int bid = blockIdx.x;            // b*128 + chunk(64 rows)
    int b = bid >> 7, chunk = bid & 127;
    int tid = threadIdx.x;
    int g = tid >> 4, s = tid & 15;  // g: row group, s: 16B slice of the 128-l K row
    float mx8[8];
#pragma unroll
    for (int j = 0; j < 8; ++j) mx8[j] = -3.0e38f;
    int t0 = chunk * 64;
#pragma unroll
    for (int p = 0; p < 4; ++p) {
        int m = b * 8192 + t0 + g + p * 16;
        uint4 kq = *(const uint4*)(QKV + (size_t)m * 1280 + 128 + s * 8);
        mx8[0] = fmaxf(mx8[0], __builtin_bit_cast(float, kq.x << 16));
        mx8[1] = fmaxf(mx8[1], __builtin_bit_cast(float, kq.x & 0xffff0000u));
        mx8[2] = fmaxf(mx8[2], __builtin_bit_cast(float, kq.y << 16));
        mx8[3] = fmaxf(mx8[3], __builtin_bit_cast(float, kq.y & 0xffff0000u));
        mx8[4] = fmaxf(mx8[4], __builtin_bit_cast(float, kq.z << 16));
        mx8[5] = fmaxf(mx8[5], __builtin_bit_cast(float, kq.z & 0xffff0000u));
        mx8[6] = fmaxf(mx8[6], __builtin_bit_cast(float, kq.w << 16));
        mx8[7] = fmaxf(mx8[7], __builtin_bit_cast(float, kq.w & 0xffff0000u));
    }
    __shared__ float red[16][128];
#pragma unroll
    for (int j = 0; j < 8; ++j) red[g][s * 8 + j] = mx8[j];
    __syncthreads();
    if (tid < 128) {
        float m = -3.0e38f;
#pragma unroll
        for (int g2 = 0; g2 < 16; ++g2) m = fmaxf(m, red[g2][tid]);
        Pmax[bid * 128 + tid] = m;
    }
}

// ---------------------------------------------------------------------------
// Partial Kv/Ksum over 256-row chunks. Block = ((b*16+h)*32 + chunk), 4 waves.
// Global K-max is now reduced in-prologue from Pmax (the old single-block
// maxreduce kernel was a pure-latency launch node).
// ---------------------------------------------------------------------------
__global__ __launch_bounds__(256) void kvpart_kernel(const u16* __restrict__ QKV,
                                                     const float* __restrict__ MC,
                                                     const float* __restrict__ Pmax,
                                                     float* __restrict__ Kvp,
                                                     float* __restrict__ Ksp) {
    int bid = blockIdx.x;
    int chunk = bid & 31;
    int bh = bid >> 5;
    int h = bh & 15, b = bh >> 4;
    int w = threadIdx.x >> 6, lane = threadIdx.x & 63;

    // ---- global max over the 128 Pmax chunks for this (b, h) ----
    __shared__ float redm[32][8];
    __shared__ float redf[8];
    {
        int jj = threadIdx.x & 7, cgx = threadIdx.x >> 3;   // cgx: 0..31
        float pm = -3.0e38f;
        for (int c = cgx; c < 128; c += 32)
            pm = fmaxf(pm, Pmax[((b * 128 + c) << 7) + h * 8 + jj]);
        redm[cgx][jj] = pm;
        __syncthreads();
        if (threadIdx.x < 8) {
            float m2 = -3.0e38f;
#pragma unroll
            for (int c2 = 0; c2 < 32; ++c2) m2 = fmaxf(m2, redm[c2][threadIdx.x]);
            redf[threadIdx.x] = m2;
        }
        __syncthreads();
    }
    float mx[8];
#pragma unroll
    for (int l = 0; l < 8; ++l) mx[l] = redf[l];

    float kv[8] = {0, 0, 0, 0, 0, 0, 0, 0};
    float ks[8] = {0, 0, 0, 0, 0, 0, 0, 0};
    int t0 = chunk * 256;
    for (int i = 0; i < 64; ++i) {
        int t = t0 + w + i * 4;
        int m = b * 8192 + t;
        const u16* row = QKV + (size_t)m * 1280;
        float v = bf2f(row[256 + h * 64 + lane]);
        uint4 kq = *(const uint4*)(row + 128 + h * 8);
        float msk = MC[b * 8192 + t];
        float vm = v * msk;
        float kf[8];
        kf[0] = __builtin_bit_cast(float, kq.x << 16);
        kf[1] = __builtin_bit_cast(float, kq.x & 0xffff0000u);
        kf[2] = __builtin_bit_cast(float, kq.y << 16);
        kf[3] = __builtin_bit_cast(float, kq.y & 0xffff0000u);
        kf[4] = __builtin_bit_cast(float, kq.z << 16);
        kf[5] = __builtin_bit_cast(float, kq.z & 0xffff0000u);
        kf[6] = __builtin_bit_cast(float, kq.w << 16);
        kf[7] = __builtin_bit_cast(float, kq.w & 0xffff0000u);
#pragma unroll
        for (int l = 0; l < 8; ++l) {
            float e = __expf(kf[l] - mx[l]) * msk;   // exp(K-max)*mask
            kv[l] += e * vm;                         // * (V*mask)
            ks[l] += e;
        }
    }
    __shared__ float red[4][8][64];
    __shared__ float redks[4][8];
#pragma unroll
    for (int l = 0; l < 8; ++l) red[w][l][lane] = kv[l];
    if (lane == 0) {
#pragma unroll
        for (int l = 0; l < 8; ++l) redks[w][l] = ks[l];
    }
    __syncthreads();
    int tid = threadIdx.x;
    for (int c = tid; c < 512; c += 256) {
        int l = c >> 6, d = c & 63;
        Kvp[bid * 512 + c] = red[0][l][d] + red[1][l][d] + red[2][l][d] + red[3][l][d];
    }
    if (tid < 8) Ksp[bid * 8 + tid] = redks[0][tid] + redks[1][tid] + redks[2][tid] + redks[3][tid];
}

__global__ void kvreduce_kernel(const float* __restrict__ Kvp, const float* __restrict__ Ksp,
                                float* __restrict__ Kv) {
    int bh = blockIdx.x;             // 64
    int tid = threadIdx.x;           // 512 = l*64+d
    int l = tid >> 6;
    float s = 0.f, ks = 0.f;
    for (int c = 0; c < 32; ++c) {
        s += Kvp[(bh * 32 + c) * 512 + tid];
        ks += Ksp[(bh * 32 + c) * 8 + l];
    }
    Kv[bh * 512 + tid] = s / ks;
}

// ---------------------------------------------------------------------------
// y[m, h*64+d] = softmax_l(Q[m,h,:]) @ Kv[b,h,l,d]; in-place over V region.
// 2048 blocks (16 rows/block): 8 blocks/CU for latency hiding.
// ---------------------------------------------------------------------------
__global__ __launch_bounds__(256) void y_kernel(u16* __restrict__ QKV,
                                                const float* __restrict__ Kv) {
    int bid = blockIdx.x;            // b*512 + chunk(16 rows)
    int b = bid >> 9, chunk = bid & 511;
    int w = threadIdx.x >> 6, lane = threadIdx.x & 63;
    int hh = w & 1;
    int rp = w >> 1;
    int hloc = lane >> 3;
    int h = hh * 8 + hloc;
    int dg = lane & 7;

    float4 kva[8], kvb[8];
    const float* kvp = Kv + (b * 16 + h) * 512 + dg * 8;
#pragma unroll
    for (int l = 0; l < 8; ++l) {
        kva[l] = *(const float4*)(kvp + l * 64);
        kvb[l] = *(const float4*)(kvp + l * 64 + 4);
    }
    int lgrp = lane & 56;
    for (int i = 0; i < 8; ++i) {
        int t = chunk * 16 + i * 2 + rp;
        int m = b * 8192 + t;
        u16* row = QKV + (size_t)m * 1280;
        float qv = bf2f(row[hh * 64 + lane]);
        float qm = qv;
        qm = fmaxf(qm, __shfl_xor(qm, 1));
        qm = fmaxf(qm, __shfl_xor(qm, 2));
        qm = fmaxf(qm, __shfl_xor(qm, 4));
        float e = __expf(qv - qm);
        float s = e;
        s += __shfl_xor(s, 1);
        s += __shfl_xor(s, 2);
        s += __shfl_xor(s, 4);
        float qs = e / s;
        float4 a0 = {0.f, 0.f, 0.f, 0.f}, a1 = {0.f, 0.f, 0.f, 0.f};
#pragma unroll
        for (int l = 0; l < 8; ++l) {
            float ql = __shfl(qs, lgrp + l);
            a0.x += ql * kva[l].x; a0.y += ql * kva[l].y;
            a0.z += ql * kva[l].z; a0.w += ql * kva[l].w;
            a1.x += ql * kvb[l].x; a1.y += ql * kvb[l].y;
            a1.z += ql * kvb[l].z; a1.w += ql * kvb[l].w;
        }
        uint4 o;
        o.x = pack2(a0.x, a0.y);
        o.y = pack2(a0.z, a0.w);
        o.z = pack2(a1.x, a1.y);
        o.w = pack2(a1.z, a1.w);
        *(uint4*)(row + 256 + h * 64 + dg * 8) = o;
    }
}

// ---------------------------------------------------------------------------
// Workspace layout (bytes). PMAX (now 512*128*4 = 256 KB) lives at the head
// of the XC region: XC's last reader is the QKV GEMM, which completes before
// maxpart writes PMAX (stream-ordered WAR), so no footprint growth.
// ---------------------------------------------------------------------------
#define OFF_FLAG ((size_t)0)                        // 2 ints
#define OFF_W1T  ((size_t)1024)                     // 1280*1024*2 = 2,621,440
#define OFF_OPT  ((size_t)2622464)                  // 1024*1024*2 = 2,097,152
#define OFF_KVP  ((size_t)4787200)                  // 2048*512*4 = 4,194,304
#define OFF_KSP  ((size_t)8981504)                  // 2048*8*4 = 65,536
#define OFF_KV   ((size_t)9047040)                  // 64*512*4 = 131,072
#define OFF_MC   ((size_t)9178112)                  // 32768*4 = 131,072
#define OFF_XC   ((size_t)9309184)                  // 33554432*2 = 67,108,864
#define OFF_QKV  ((size_t)76418048)                 // 32768*1280*2 = 83,886,080
// total = 160,304,128 bytes

extern "C" void kernel_launch(void* const* d_in, const int* in_sizes, int n_in,
                              void* d_out, int out_size, void* d_ws, size_t ws_size,
                              hipStream_t stream) {
    const u16* X   = (const u16*)d_in[0];
    const void* msk = d_in[1];
    const void* Wk  = d_in[2];
    const void* Wq  = d_in[3];
    const void* Wv  = d_in[4];
    const void* Op  = d_in[5];

    char* ws = (char*)d_ws;
    int*   FLAGS = (int*)(ws + OFF_FLAG);
    u16*   W1T  = (u16*)(ws + OFF_W1T);
    u16*   OPT  = (u16*)(ws + OFF_OPT);
    float* KVP  = (float*)(ws + OFF_KVP);
    float* KSP  = (float*)(ws + OFF_KSP);
    float* KV   = (float*)(ws + OFF_KV);
    float* MC   = (float*)(ws + OFF_MC);
    u16*   XC   = (u16*)(ws + OFF_XC);
    float* PMAX = (float*)(ws + OFF_XC);             // aliases XC (dead by then)
    u16*   QKV  = (u16*)(ws + OFF_QKV);

    // 0) detect input dtype (flags[0]=1 -> fp32), flags[1]=0 always
    detect_kernel<<<1, 256, 0, stream>>>(X, FLAGS);
    // 0b) canonicalize X (no-op if bf16) and mask (always fp32 canonical)
    convert_x<<<16384, 256, 0, stream>>>((const float*)d_in[0], XC, FLAGS, 33554432);
    convert_mask<<<128, 256, 0, stream>>>(msk, MC, FLAGS, 32768);
    // 1) transpose weights to (N,K) bf16 (dual-dtype reads)
    transpose_k<<<2304, 256, 0, stream>>>(Wq, Wk, Wv, Op, W1T, OPT, FLAGS);
    // 2) fused QKV projection: QKV[m,0:128)=Q, [128:256)=K, [256:1280)=V
    gemm_bt<<<2560, 256, 0, stream>>>(X, XC, 1024, W1T, 1024, QKV, 1280, 256, 1024,
                                      FLAGS, FLAGS + 1);
    // 3) partial max of K over T (global reduce folded into kvpart prologue)
    maxpart_kernel<<<512, 256, 0, stream>>>(QKV, PMAX);
    // 4) Kv state + Ksum
    kvpart_kernel<<<2048, 256, 0, stream>>>(QKV, MC, PMAX, KVP, KSP);
    kvreduce_kernel<<<64, 512, 0, stream>>>(KVP, KSP, KV);
    // 5) y = softmax(Q) @ Kv, in-place over V region
    y_kernel<<<2048, 256, 0, stream>>>(QKV, KV);
    // 6) out = y @ o_proj (output dtype per detected flag)
    gemm_bt<<<2048, 256, 0, stream>>>(QKV + 256, QKV + 256, 1280, OPT, 1024,
                                      d_out, 1024, 256, 1024, FLAGS + 1, FLAGS);
}

// Round 9
// 579.436 us; speedup vs baseline: 6.2628x; 1.0387x over previous
//
#include <hip/hip_runtime.h>
#include <hip/hip_bf16.h>

typedef unsigned short u16;
typedef unsigned int   u32;

typedef __attribute__((ext_vector_type(8))) short short8;
typedef __attribute__((ext_vector_type(4))) float f32x4;

typedef const __attribute__((address_space(1))) void g_void;
typedef __attribute__((address_space(3))) void l_void;

__device__ __forceinline__ float bf2f(u16 u) {
    u32 x = ((u32)u) << 16;
    return __builtin_bit_cast(float, x);
}
__device__ __forceinline__ u16 f2bf(float f) {
    u32 u = __builtin_bit_cast(u32, f);
    u32 r = (u + 0x7FFFu + ((u >> 16) & 1u)) >> 16;
    return (u16)r;
}
__device__ __forceinline__ u32 pack2(float a, float b) {
    return (u32)f2bf(a) | ((u32)f2bf(b) << 16);
}

// ---------------------------------------------------------------------------
// Dtype detector: reads first 16384 u16 words of X. bf16 data -> ~100% sane
// exponent fields; fp32 data reinterpreted as u16 -> ~57%. flags[0]=1 => fp32.
// flags[1] is a guaranteed-zero word used by consumers needing "always bf16".
// ---------------------------------------------------------------------------
__global__ void detect_kernel(const u16* __restrict__ X, int* __restrict__ flags) {
    __shared__ int cnt[256];
    int c = 0;
    for (int i = threadIdx.x; i < 16384; i += 256) {
        u16 v = X[i];
        int e = (v >> 7) & 0xFF;
        c += (e >= 104 && e <= 140) ? 1 : 0;
    }
    cnt[threadIdx.x] = c;
    __syncthreads();
    for (int s = 128; s > 0; s >>= 1) {
        if (threadIdx.x < s) cnt[threadIdx.x] += cnt[threadIdx.x + s];
        __syncthreads();
    }
    if (threadIdx.x == 0) {
        flags[0] = (cnt[0] < 14746) ? 1 : 0;   // <90% sane => fp32
        flags[1] = 0;
    }
}

// X canonicalization: only does work when input is fp32 (copies to bf16 XC).
__global__ __launch_bounds__(256) void convert_x(const float* __restrict__ Xf,
                                                 u16* __restrict__ XC,
                                                 const int* __restrict__ flags, int n) {
    if (flags[0] == 0) return;
    int i = (blockIdx.x * 256 + threadIdx.x) * 8;
    if (i >= n) return;
    float4 a = *(const float4*)(Xf + i);
    float4 b = *(const float4*)(Xf + i + 4);
    uint4 o;
    o.x = pack2(a.x, a.y); o.y = pack2(a.z, a.w);
    o.z = pack2(b.x, b.y); o.w = pack2(b.z, b.w);
    *(uint4*)(XC + i) = o;
}

// mask canonicalization to fp32 (always runs; tiny).
__global__ void convert_mask(const void* __restrict__ m, float* __restrict__ MC,
                             const int* __restrict__ flags, int n) {
    int i = blockIdx.x * 256 + threadIdx.x;
    if (i >= n) return;
    MC[i] = flags[0] ? ((const float*)m)[i] : bf2f(((const u16*)m)[i]);
}

// ---------------------------------------------------------------------------
// GEMM: C(MxN, ldc) = A(MxK, bf16, lda) * Bt(NxK, bf16, ldb)^T
// 128x128 tile, BK=32, 4 waves (2x2), 16x16x32 bf16 MFMA.
// Round-8 change: XCD-chunked blockIdx swizzle (T1). Round-5's plain mt-major
// order put the 10 nt-blocks sharing an A-panel on 8 DIFFERENT XCDs (dispatch
// round-robins bid across XCDs) -> each A-panel fetched into multiple private
// L2s; FETCH measured 290 MB vs ~67 MB ideal. The swizzle gives each XCD a
// contiguous mt-major chunk of tile space, so A-panel sharers run on ONE XCD.
// Grids are divisible by 8 so the simple bijective form is valid.
// Epilogue: stride-132 bank pad (conflicts 3.28M -> 0, verified R8).
// ---------------------------------------------------------------------------
__global__ __launch_bounds__(256) void gemm_bt(
    const u16* __restrict__ A0, const u16* __restrict__ A1, int lda,
    const u16* __restrict__ Bt, int ldb,
    void* __restrict__ C, int ldc,
    int Mtiles, int K,
    const int* __restrict__ aselp, const int* __restrict__ ofp) {
    __shared__ char smem[17408];

    const u16* A = aselp[0] ? A1 : A0;

    const int tid = threadIdx.x;
    const int w = tid >> 6, lane = tid & 63;
    const int Ntiles = gridDim.x / Mtiles;
    // XCD-chunked swizzle: xcd = bid & 7 owns tiles [xcd*q8, (xcd+1)*q8)
    const int q8 = gridDim.x >> 3;
    const int t  = (blockIdx.x & 7) * q8 + (blockIdx.x >> 3);
    const int mt = t / Ntiles;
    const int nt = t % Ntiles;
    const int m0 = mt << 7, n0 = nt << 7;
    const int wm = w >> 1, wn = w & 1;

    f32x4 acc[4][4] = {};

    // staging: row rr = w*16 + lane/4 (plus +64 for second store),
    // LDS slot s = lane&3 holds global chunk cg = s ^ swz(row), swz(r)=(r>>1)&3
    const int rr = w * 16 + (lane >> 2);
    const int cg = (lane & 3) ^ ((lane >> 3) & 3);

    const u16* gA0 = A + (m0 + rr) * lda + cg * 8;
    const u16* gA1 = A + (m0 + rr + 64) * lda + cg * 8;
    const u16* gB0 = Bt + (n0 + rr) * ldb + cg * 8;
    const u16* gB1 = Bt + (n0 + rr + 64) * ldb + cg * 8;

    // linear LDS destinations (lane*16 within each wave's 1KB strip)
    char* lA0 = smem + w * 1024 + lane * 16;
    char* lA1 = smem + 4096 + w * 1024 + lane * 16;
    char* lB0 = smem + 8192 + w * 1024 + lane * 16;
    char* lB1 = smem + 12288 + w * 1024 + lane * 16;

    // fragment reads: row = wm*64 + mi*16 + (lane&15), chunk q = lane>>4,
    // slot = q ^ ((lane>>1)&3)
    const int fr_a = (wm << 6) + (lane & 15);
    const int fr_b = (wn << 6) + (lane & 15);
    const int sl = (lane >> 4) ^ ((lane >> 1) & 3);
    const char* pA = smem + fr_a * 64 + sl * 16;
    const char* pB = smem + 8192 + fr_b * 64 + sl * 16;

    for (int kt = 0; kt < K; kt += 32) {
        __builtin_amdgcn_global_load_lds((g_void*)(gA0 + kt), (l_void*)lA0, 16, 0, 0);
        __builtin_amdgcn_global_load_lds((g_void*)(gA1 + kt), (l_void*)lA1, 16, 0, 0);
        __builtin_amdgcn_global_load_lds((g_void*)(gB0 + kt), (l_void*)lB0, 16, 0, 0);
        __builtin_amdgcn_global_load_lds((g_void*)(gB1 + kt), (l_void*)lB1, 16, 0, 0);
        __syncthreads();
        short8 af[4], bfv[4];
#pragma unroll
        for (int i = 0; i < 4; ++i) {
            af[i]  = *(const short8*)(pA + i * 1024);
            bfv[i] = *(const short8*)(pB + i * 1024);
        }
#pragma unroll
        for (int mi = 0; mi < 4; ++mi) {
#pragma unroll
            for (int ni = 0; ni < 4; ++ni) {
                acc[mi][ni] = __builtin_amdgcn_mfma_f32_16x16x32_bf16(
                    af[mi], bfv[ni], acc[mi][ni], 0, 0, 0);
            }
        }
        __syncthreads();
    }

    // epilogue: repack 32-row strips through LDS (stride 132 = bank pad);
    // fully unrolled so every acc index is compile-time constant (rule #20).
    const int out_fp32 = ofp[0];
    float* fb = (float*)smem;
    const int lrow = tid >> 3, cgp = tid & 7;
#pragma unroll
    for (int mi = 0; mi < 4; ++mi) {
#pragma unroll
        for (int ni = 0; ni < 4; ++ni) {
#pragma unroll
            for (int r = 0; r < 4; ++r) {
                int lr = wm * 16 + ((lane >> 4) << 2) + r;
                int lc = wn * 64 + ni * 16 + (lane & 15);
                fb[lr * 132 + lc] = acc[mi][ni][r];
            }
        }
        __syncthreads();
        int grow = (lrow < 16) ? (mi * 16 + lrow) : (48 + mi * 16 + lrow);
        const float* srcp = fb + lrow * 132 + cgp * 16;
        if (out_fp32) {
            float4* dst = (float4*)((float*)C + (size_t)(m0 + grow) * ldc + n0 + cgp * 16);
            dst[0] = make_float4(srcp[0], srcp[1], srcp[2], srcp[3]);
            dst[1] = make_float4(srcp[4], srcp[5], srcp[6], srcp[7]);
            dst[2] = make_float4(srcp[8], srcp[9], srcp[10], srcp[11]);
            dst[3] = make_float4(srcp[12], srcp[13], srcp[14], srcp[15]);
        } else {
            u32 o0 = pack2(srcp[0], srcp[1]);
            u32 o1 = pack2(srcp[2], srcp[3]);
            u32 o2 = pack2(srcp[4], srcp[5]);
            u32 o3 = pack2(srcp[6], srcp[7]);
            u32 o4 = pack2(srcp[8], srcp[9]);
            u32 o5 = pack2(srcp[10], srcp[11]);
            u32 o6 = pack2(srcp[12], srcp[13]);
            u32 o7 = pack2(srcp[14], srcp[15]);
            uint4* dst = (uint4*)((u16*)C + (size_t)(m0 + grow) * ldc + n0 + cgp * 16);
            dst[0] = make_uint4(o0, o1, o2, o3);
            dst[1] = make_uint4(o4, o5, o6, o7);
        }
        __syncthreads();
    }
}

// ---------------------------------------------------------------------------
// Transpose weights into (N,K) row-major bf16, dual-dtype source reads.
// W1T rows [0,128)=Wq^T, [128,256)=Wk^T, [256,1280)=Wv^T; OpT = o_proj^T.
// ---------------------------------------------------------------------------
__device__ __forceinline__ u16 rd_elem(const void* s, int idx, int fp32) {
    return fp32 ? f2bf(((const float*)s)[idx]) : ((const u16*)s)[idx];
}

__global__ void transpose_k(const void* __restrict__ Wq, const void* __restrict__ Wk,
                            const void* __restrict__ Wv, const void* __restrict__ Op,
                            u16* __restrict__ W1T, u16* __restrict__ OpT,
                            const int* __restrict__ flags) {
    int fp32 = flags[0];
    int id = blockIdx.x;
    const void* src; u16* dst; int Nc, mid;
    if (id < 128)       { src = Wq; dst = W1T;               Nc = 128;  mid = id; }
    else if (id < 256)  { src = Wk; dst = W1T + 128 * 1024;  Nc = 128;  mid = id - 128; }
    else if (id < 1280) { src = Wv; dst = W1T + 256 * 1024;  Nc = 1024; mid = id - 256; }
    else                { src = Op; dst = OpT;               Nc = 1024; mid = id - 1280; }
    int kt = mid & 31, nt = mid >> 5;
    __shared__ u16 tile[32][33];
    int x = threadIdx.x & 31, y0 = threadIdx.x >> 5;
#pragma unroll
    for (int yy = 0; yy < 4; ++yy) {
        int y = y0 * 4 + yy;
        tile[y][x] = rd_elem(src, (kt * 32 + y) * Nc + nt * 32 + x, fp32);
    }
    __syncthreads();
#pragma unroll
    for (int yy = 0; yy < 4; ++yy) {
        int y = y0 * 4 + yy;
        dst[(nt * 32 + y) * 1024 + kt * 32 + x] = tile[x][y];
    }
}

// ---------------------------------------------------------------------------
// Partial max of K over 64-row chunks: Pmax[b*128+chunk][128].
// 512 blocks, uint4 coalesced loads.
// ---------------------------------------------------------------------------
__global__ __launch_bounds__(256) void maxpart_kernel(const u16* __restrict__ QKV,
                                                      float* __restrict__ Pmax) {
    int bid = blockIdx.x;            // b*128 + chunk(64 rows)
    int b = bid >> 7, chunk = bid & 127;
    int tid = threadIdx.x;
    int g = tid >> 4, s = tid & 15;  // g: row group, s: 16B slice of the 128-l K row
    float mx8[8];
#pragma unroll
    for (int j = 0; j < 8; ++j) mx8[j] = -3.0e38f;
    int t0 = chunk * 64;
#pragma unroll
    for (int p = 0; p < 4; ++p) {
        int m = b * 8192 + t0 + g + p * 16;
        uint4 kq = *(const uint4*)(QKV + (size_t)m * 1280 + 128 + s * 8);
        mx8[0] = fmaxf(mx8[0], __builtin_bit_cast(float, kq.x << 16));
        mx8[1] = fmaxf(mx8[1], __builtin_bit_cast(float, kq.x & 0xffff0000u));
        mx8[2] = fmaxf(mx8[2], __builtin_bit_cast(float, kq.y << 16));
        mx8[3] = fmaxf(mx8[3], __builtin_bit_cast(float, kq.y & 0xffff0000u));
        mx8[4] = fmaxf(mx8[4], __builtin_bit_cast(float, kq.z << 16));
        mx8[5] = fmaxf(mx8[5], __builtin_bit_cast(float, kq.z & 0xffff0000u));
        mx8[6] = fmaxf(mx8[6], __builtin_bit_cast(float, kq.w << 16));
        mx8[7] = fmaxf(mx8[7], __builtin_bit_cast(float, kq.w & 0xffff0000u));
    }
    __shared__ float red[16][128];
#pragma unroll
    for (int j = 0; j < 8; ++j) red[g][s * 8 + j] = mx8[j];
    __syncthreads();
    if (tid < 128) {
        float m = -3.0e38f;
#pragma unroll
        for (int g2 = 0; g2 < 16; ++g2) m = fmaxf(m, red[g2][tid]);
        Pmax[bid * 128 + tid] = m;
    }
}

// ---------------------------------------------------------------------------
// Partial Kv/Ksum over 256-row chunks. Block = ((b*16+h)*32 + chunk), 4 waves.
// Global K-max reduced in-prologue from Pmax.
// ---------------------------------------------------------------------------
__global__ __launch_bounds__(256) void kvpart_kernel(const u16* __restrict__ QKV,
                                                     const float* __restrict__ MC,
                                                     const float* __restrict__ Pmax,
                                                     float* __restrict__ Kvp,
                                                     float* __restrict__ Ksp) {
    int bid = blockIdx.x;
    int chunk = bid & 31;
    int bh = bid >> 5;
    int h = bh & 15, b = bh >> 4;
    int w = threadIdx.x >> 6, lane = threadIdx.x & 63;

    // ---- global max over the 128 Pmax chunks for this (b, h) ----
    __shared__ float redm[32][8];
    __shared__ float redf[8];
    {
        int jj = threadIdx.x & 7, cgx = threadIdx.x >> 3;   // cgx: 0..31
        float pm = -3.0e38f;
        for (int c = cgx; c < 128; c += 32)
            pm = fmaxf(pm, Pmax[((b * 128 + c) << 7) + h * 8 + jj]);
        redm[cgx][jj] = pm;
        __syncthreads();
        if (threadIdx.x < 8) {
            float m2 = -3.0e38f;
#pragma unroll
            for (int c2 = 0; c2 < 32; ++c2) m2 = fmaxf(m2, redm[c2][threadIdx.x]);
            redf[threadIdx.x] = m2;
        }
        __syncthreads();
    }
    float mx[8];
#pragma unroll
    for (int l = 0; l < 8; ++l) mx[l] = redf[l];

    float kv[8] = {0, 0, 0, 0, 0, 0, 0, 0};
    float ks[8] = {0, 0, 0, 0, 0, 0, 0, 0};
    int t0 = chunk * 256;
    for (int i = 0; i < 64; ++i) {
        int t = t0 + w + i * 4;
        int m = b * 8192 + t;
        const u16* row = QKV + (size_t)m * 1280;
        float v = bf2f(row[256 + h * 64 + lane]);
        uint4 kq = *(const uint4*)(row + 128 + h * 8);
        float msk = MC[b * 8192 + t];
        float vm = v * msk;
        float kf[8];
        kf[0] = __builtin_bit_cast(float, kq.x << 16);
        kf[1] = __builtin_bit_cast(float, kq.x & 0xffff0000u);
        kf[2] = __builtin_bit_cast(float, kq.y << 16);
        kf[3] = __builtin_bit_cast(float, kq.y & 0xffff0000u);
        kf[4] = __builtin_bit_cast(float, kq.z << 16);
        kf[5] = __builtin_bit_cast(float, kq.z & 0xffff0000u);
        kf[6] = __builtin_bit_cast(float, kq.w << 16);
        kf[7] = __builtin_bit_cast(float, kq.w & 0xffff0000u);
#pragma unroll
        for (int l = 0; l < 8; ++l) {
            float e = __expf(kf[l] - mx[l]) * msk;   // exp(K-max)*mask
            kv[l] += e * vm;                         // * (V*mask)
            ks[l] += e;
        }
    }
    __shared__ float red[4][8][64];
    __shared__ float redks[4][8];
#pragma unroll
    for (int l = 0; l < 8; ++l) red[w][l][lane] = kv[l];
    if (lane == 0) {
#pragma unroll
        for (int l = 0; l < 8; ++l) redks[w][l] = ks[l];
    }
    __syncthreads();
    int tid = threadIdx.x;
    for (int c = tid; c < 512; c += 256) {
        int l = c >> 6, d = c & 63;
        Kvp[bid * 512 + c] = red[0][l][d] + red[1][l][d] + red[2][l][d] + red[3][l][d];
    }
    if (tid < 8) Ksp[bid * 8 + tid] = redks[0][tid] + redks[1][tid] + redks[2][tid] + redks[3][tid];
}

__global__ void kvreduce_kernel(const float* __restrict__ Kvp, const float* __restrict__ Ksp,
                                float* __restrict__ Kv) {
    int bh = blockIdx.x;             // 64
    int tid = threadIdx.x;           // 512 = l*64+d
    int l = tid >> 6;
    float s = 0.f, ks = 0.f;
    for (int c = 0; c < 32; ++c) {
        s += Kvp[(bh * 32 + c) * 512 + tid];
        ks += Ksp[(bh * 32 + c) * 8 + l];
    }
    Kv[bh * 512 + tid] = s / ks;
}

// ---------------------------------------------------------------------------
// y[m, h*64+d] = softmax_l(Q[m,h,:]) @ Kv[b,h,l,d]; in-place over V region.
// 2048 blocks (16 rows/block): 8 blocks/CU for latency hiding.
// ---------------------------------------------------------------------------
__global__ __launch_bounds__(256) void y_kernel(u16* __restrict__ QKV,
                                                const float* __restrict__ Kv) {
    int bid = blockIdx.x;            // b*512 + chunk(16 rows)
    int b = bid >> 9, chunk = bid & 511;
    int w = threadIdx.x >> 6, lane = threadIdx.x & 63;
    int hh = w & 1;
    int rp = w >> 1;
    int hloc = lane >> 3;
    int h = hh * 8 + hloc;
    int dg = lane & 7;

    float4 kva[8], kvb[8];
    const float* kvp = Kv + (b * 16 + h) * 512 + dg * 8;
#pragma unroll
    for (int l = 0; l < 8; ++l) {
        kva[l] = *(const float4*)(kvp + l * 64);
        kvb[l] = *(const float4*)(kvp + l * 64 + 4);
    }
    int lgrp = lane & 56;
    for (int i = 0; i < 8; ++i) {
        int t = chunk * 16 + i * 2 + rp;
        int m = b * 8192 + t;
        u16* row = QKV + (size_t)m * 1280;
        float qv = bf2f(row[hh * 64 + lane]);
        float qm = qv;
        qm = fmaxf(qm, __shfl_xor(qm, 1));
        qm = fmaxf(qm, __shfl_xor(qm, 2));
        qm = fmaxf(qm, __shfl_xor(qm, 4));
        float e = __expf(qv - qm);
        float s = e;
        s += __shfl_xor(s, 1);
        s += __shfl_xor(s, 2);
        s += __shfl_xor(s, 4);
        float qs = e / s;
        float4 a0 = {0.f, 0.f, 0.f, 0.f}, a1 = {0.f, 0.f, 0.f, 0.f};
#pragma unroll
        for (int l = 0; l < 8; ++l) {
            float ql = __shfl(qs, lgrp + l);
            a0.x += ql * kva[l].x; a0.y += ql * kva[l].y;
            a0.z += ql * kva[l].z; a0.w += ql * kva[l].w;
            a1.x += ql * kvb[l].x; a1.y += ql * kvb[l].y;
            a1.z += ql * kvb[l].z; a1.w += ql * kvb[l].w;
        }
        uint4 o;
        o.x = pack2(a0.x, a0.y);
        o.y = pack2(a0.z, a0.w);
        o.z = pack2(a1.x, a1.y);
        o.w = pack2(a1.z, a1.w);
        *(uint4*)(row + 256 + h * 64 + dg * 8) = o;
    }
}

// ---------------------------------------------------------------------------
// Workspace layout (bytes). PMAX (512*128*4 = 256 KB) aliases the head of the
// XC region (dead after the QKV GEMM reads it; stream-ordered WAR).
// ---------------------------------------------------------------------------
#define OFF_FLAG ((size_t)0)                        // 2 ints
#define OFF_W1T  ((size_t)1024)                     // 1280*1024*2 = 2,621,440
#define OFF_OPT  ((size_t)2622464)                  // 1024*1024*2 = 2,097,152
#define OFF_KVP  ((size_t)4787200)                  // 2048*512*4 = 4,194,304
#define OFF_KSP  ((size_t)8981504)                  // 2048*8*4 = 65,536
#define OFF_KV   ((size_t)9047040)                  // 64*512*4 = 131,072
#define OFF_MC   ((size_t)9178112)                  // 32768*4 = 131,072
#define OFF_XC   ((size_t)9309184)                  // 33554432*2 = 67,108,864
#define OFF_QKV  ((size_t)76418048)                 // 32768*1280*2 = 83,886,080
// total = 160,304,128 bytes

extern "C" void kernel_launch(void* const* d_in, const int* in_sizes, int n_in,
                              void* d_out, int out_size, void* d_ws, size_t ws_size,
                              hipStream_t stream) {
    const u16* X   = (const u16*)d_in[0];
    const void* msk = d_in[1];
    const void* Wk  = d_in[2];
    const void* Wq  = d_in[3];
    const void* Wv  = d_in[4];
    const void* Op  = d_in[5];

    char* ws = (char*)d_ws;
    int*   FLAGS = (int*)(ws + OFF_FLAG);
    u16*   W1T  = (u16*)(ws + OFF_W1T);
    u16*   OPT  = (u16*)(ws + OFF_OPT);
    float* KVP  = (float*)(ws + OFF_KVP);
    float* KSP  = (float*)(ws + OFF_KSP);
    float* KV   = (float*)(ws + OFF_KV);
    float* MC   = (float*)(ws + OFF_MC);
    u16*   XC   = (u16*)(ws + OFF_XC);
    float* PMAX = (float*)(ws + OFF_XC);             // aliases XC (dead by then)
    u16*   QKV  = (u16*)(ws + OFF_QKV);

    // 0) detect input dtype (flags[0]=1 -> fp32), flags[1]=0 always
    detect_kernel<<<1, 256, 0, stream>>>(X, FLAGS);
    // 0b) canonicalize X (no-op if bf16) and mask (always fp32 canonical)
    convert_x<<<16384, 256, 0, stream>>>((const float*)d_in[0], XC, FLAGS, 33554432);
    convert_mask<<<128, 256, 0, stream>>>(msk, MC, FLAGS, 32768);
    // 1) transpose weights to (N,K) bf16 (dual-dtype reads)
    transpose_k<<<2304, 256, 0, stream>>>(Wq, Wk, Wv, Op, W1T, OPT, FLAGS);
    // 2) fused QKV projection: QKV[m,0:128)=Q, [128:256)=K, [256:1280)=V
    gemm_bt<<<2560, 256, 0, stream>>>(X, XC, 1024, W1T, 1024, QKV, 1280, 256, 1024,
                                      FLAGS, FLAGS + 1);
    // 3) partial max of K over T (global reduce folded into kvpart prologue)
    maxpart_kernel<<<512, 256, 0, stream>>>(QKV, PMAX);
    // 4) Kv state + Ksum
    kvpart_kernel<<<2048, 256, 0, stream>>>(QKV, MC, PMAX, KVP, KSP);
    kvreduce_kernel<<<64, 512, 0, stream>>>(KVP, KSP, KV);
    // 5) y = softmax(Q) @ Kv, in-place over V region
    y_kernel<<<2048, 256, 0, stream>>>(QKV, KV);
    // 6) out = y @ o_proj (output dtype per detected flag)
    gemm_bt<<<2048, 256, 0, stream>>>(QKV + 256, QKV + 256, 1280, OPT, 1024,
                                      d_out, 1024, 256, 1024, FLAGS + 1, FLAGS);
}

// Round 10
// 573.957 us; speedup vs baseline: 6.3226x; 1.0095x over previous
//
#include <hip/hip_runtime.h>
#include <hip/hip_bf16.h>

typedef unsigned short u16;
typedef unsigned int   u32;

typedef __attribute__((ext_vector_type(8))) short short8;
typedef __attribute__((ext_vector_type(4))) float f32x4;

typedef const __attribute__((address_space(1))) void g_void;
typedef __attribute__((address_space(3))) void l_void;

__device__ __forceinline__ float bf2f(u16 u) {
    u32 x = ((u32)u) << 16;
    return __builtin_bit_cast(float, x);
}
__device__ __forceinline__ u16 f2bf(float f) {
    u32 u = __builtin_bit_cast(u32, f);
    u32 r = (u + 0x7FFFu + ((u >> 16) & 1u)) >> 16;
    return (u16)r;
}
__device__ __forceinline__ u32 pack2(float a, float b) {
    return (u32)f2bf(a) | ((u32)f2bf(b) << 16);
}

// ---------------------------------------------------------------------------
// Dtype detector: reads first 16384 u16 words of X. bf16 data -> ~100% sane
// exponent fields; fp32 data reinterpreted as u16 -> ~57%. flags[0]=1 => fp32.
// flags[1] is a guaranteed-zero word used by consumers needing "always bf16".
// ---------------------------------------------------------------------------
__global__ void detect_kernel(const u16* __restrict__ X, int* __restrict__ flags) {
    __shared__ int cnt[256];
    int c = 0;
    for (int i = threadIdx.x; i < 16384; i += 256) {
        u16 v = X[i];
        int e = (v >> 7) & 0xFF;
        c += (e >= 104 && e <= 140) ? 1 : 0;
    }
    cnt[threadIdx.x] = c;
    __syncthreads();
    for (int s = 128; s > 0; s >>= 1) {
        if (threadIdx.x < s) cnt[threadIdx.x] += cnt[threadIdx.x + s];
        __syncthreads();
    }
    if (threadIdx.x == 0) {
        flags[0] = (cnt[0] < 14746) ? 1 : 0;   // <90% sane => fp32
        flags[1] = 0;
    }
}

// X canonicalization: only does work when input is fp32 (copies to bf16 XC).
__global__ __launch_bounds__(256) void convert_x(const float* __restrict__ Xf,
                                                 u16* __restrict__ XC,
                                                 const int* __restrict__ flags, int n) {
    if (flags[0] == 0) return;
    int i = (blockIdx.x * 256 + threadIdx.x) * 8;
    if (i >= n) return;
    float4 a = *(const float4*)(Xf + i);
    float4 b = *(const float4*)(Xf + i + 4);
    uint4 o;
    o.x = pack2(a.x, a.y); o.y = pack2(a.z, a.w);
    o.z = pack2(b.x, b.y); o.w = pack2(b.z, b.w);
    *(uint4*)(XC + i) = o;
}

// ---------------------------------------------------------------------------
// GEMM: C(MxN, ldc) = A(MxK, bf16, lda) * Bt(NxK, bf16, ldb)^T
// 128x128 tile, BK=32, 4 waves (2x2), 16x16x32 bf16 MFMA.
// R8: XCD-chunked blockIdx swizzle (T1) -> FETCH 290->79 MB (verified R9).
// Epilogue: stride-132 bank pad (conflicts 3.28M -> 0, verified R8).
// ---------------------------------------------------------------------------
__global__ __launch_bounds__(256) void gemm_bt(
    const u16* __restrict__ A0, const u16* __restrict__ A1, int lda,
    const u16* __restrict__ Bt, int ldb,
    void* __restrict__ C, int ldc,
    int Mtiles, int K,
    const int* __restrict__ aselp, const int* __restrict__ ofp) {
    __shared__ char smem[17408];

    const u16* A = aselp[0] ? A1 : A0;

    const int tid = threadIdx.x;
    const int w = tid >> 6, lane = tid & 63;
    const int Ntiles = gridDim.x / Mtiles;
    // XCD-chunked swizzle: xcd = bid & 7 owns tiles [xcd*q8, (xcd+1)*q8)
    const int q8 = gridDim.x >> 3;
    const int t  = (blockIdx.x & 7) * q8 + (blockIdx.x >> 3);
    const int mt = t / Ntiles;
    const int nt = t % Ntiles;
    const int m0 = mt << 7, n0 = nt << 7;
    const int wm = w >> 1, wn = w & 1;

    f32x4 acc[4][4] = {};

    // staging: row rr = w*16 + lane/4 (plus +64 for second store),
    // LDS slot s = lane&3 holds global chunk cg = s ^ swz(row), swz(r)=(r>>1)&3
    const int rr = w * 16 + (lane >> 2);
    const int cg = (lane & 3) ^ ((lane >> 3) & 3);

    const u16* gA0 = A + (m0 + rr) * lda + cg * 8;
    const u16* gA1 = A + (m0 + rr + 64) * lda + cg * 8;
    const u16* gB0 = Bt + (n0 + rr) * ldb + cg * 8;
    const u16* gB1 = Bt + (n0 + rr + 64) * ldb + cg * 8;

    // linear LDS destinations (lane*16 within each wave's 1KB strip)
    char* lA0 = smem + w * 1024 + lane * 16;
    char* lA1 = smem + 4096 + w * 1024 + lane * 16;
    char* lB0 = smem + 8192 + w * 1024 + lane * 16;
    char* lB1 = smem + 12288 + w * 1024 + lane * 16;

    // fragment reads: row = wm*64 + mi*16 + (lane&15), chunk q = lane>>4,
    // slot = q ^ ((lane>>1)&3)
    const int fr_a = (wm << 6) + (lane & 15);
    const int fr_b = (wn << 6) + (lane & 15);
    const int sl = (lane >> 4) ^ ((lane >> 1) & 3);
    const char* pA = smem + fr_a * 64 + sl * 16;
    const char* pB = smem + 8192 + fr_b * 64 + sl * 16;

    for (int kt = 0; kt < K; kt += 32) {
        __builtin_amdgcn_global_load_lds((g_void*)(gA0 + kt), (l_void*)lA0, 16, 0, 0);
        __builtin_amdgcn_global_load_lds((g_void*)(gA1 + kt), (l_void*)lA1, 16, 0, 0);
        __builtin_amdgcn_global_load_lds((g_void*)(gB0 + kt), (l_void*)lB0, 16, 0, 0);
        __builtin_amdgcn_global_load_lds((g_void*)(gB1 + kt), (l_void*)lB1, 16, 0, 0);
        __syncthreads();
        short8 af[4], bfv[4];
#pragma unroll
        for (int i = 0; i < 4; ++i) {
            af[i]  = *(const short8*)(pA + i * 1024);
            bfv[i] = *(const short8*)(pB + i * 1024);
        }
#pragma unroll
        for (int mi = 0; mi < 4; ++mi) {
#pragma unroll
            for (int ni = 0; ni < 4; ++ni) {
                acc[mi][ni] = __builtin_amdgcn_mfma_f32_16x16x32_bf16(
                    af[mi], bfv[ni], acc[mi][ni], 0, 0, 0);
            }
        }
        __syncthreads();
    }

    // epilogue: repack 32-row strips through LDS (stride 132 = bank pad);
    // fully unrolled so every acc index is compile-time constant (rule #20).
    const int out_fp32 = ofp[0];
    float* fb = (float*)smem;
    const int lrow = tid >> 3, cgp = tid & 7;
#pragma unroll
    for (int mi = 0; mi < 4; ++mi) {
#pragma unroll
        for (int ni = 0; ni < 4; ++ni) {
#pragma unroll
            for (int r = 0; r < 4; ++r) {
                int lr = wm * 16 + ((lane >> 4) << 2) + r;
                int lc = wn * 64 + ni * 16 + (lane & 15);
                fb[lr * 132 + lc] = acc[mi][ni][r];
            }
        }
        __syncthreads();
        int grow = (lrow < 16) ? (mi * 16 + lrow) : (48 + mi * 16 + lrow);
        const float* srcp = fb + lrow * 132 + cgp * 16;
        if (out_fp32) {
            float4* dst = (float4*)((float*)C + (size_t)(m0 + grow) * ldc + n0 + cgp * 16);
            dst[0] = make_float4(srcp[0], srcp[1], srcp[2], srcp[3]);
            dst[1] = make_float4(srcp[4], srcp[5], srcp[6], srcp[7]);
            dst[2] = make_float4(srcp[8], srcp[9], srcp[10], srcp[11]);
            dst[3] = make_float4(srcp[12], srcp[13], srcp[14], srcp[15]);
        } else {
            u32 o0 = pack2(srcp[0], srcp[1]);
            u32 o1 = pack2(srcp[2], srcp[3]);
            u32 o2 = pack2(srcp[4], srcp[5]);
            u32 o3 = pack2(srcp[6], srcp[7]);
            u32 o4 = pack2(srcp[8], srcp[9]);
            u32 o5 = pack2(srcp[10], srcp[11]);
            u32 o6 = pack2(srcp[12], srcp[13]);
            u32 o7 = pack2(srcp[14], srcp[15]);
            uint4* dst = (uint4*)((u16*)C + (size_t)(m0 + grow) * ldc + n0 + cgp * 16);
            dst[0] = make_uint4(o0, o1, o2, o3);
            dst[1] = make_uint4(o4, o5, o6, o7);
        }
        __syncthreads();
    }
}

// ---------------------------------------------------------------------------
// Transpose weights into (N,K) row-major bf16, dual-dtype source reads.
// W1T rows [0,128)=Wq^T, [128,256)=Wk^T, [256,1280)=Wv^T; OpT = o_proj^T.
// ---------------------------------------------------------------------------
__device__ __forceinline__ u16 rd_elem(const void* s, int idx, int fp32) {
    return fp32 ? f2bf(((const float*)s)[idx]) : ((const u16*)s)[idx];
}

__global__ void transpose_k(const void* __restrict__ Wq, const void* __restrict__ Wk,
                            const void* __restrict__ Wv, const void* __restrict__ Op,
                            u16* __restrict__ W1T, u16* __restrict__ OpT,
                            const int* __restrict__ flags) {
    int fp32 = flags[0];
    int id = blockIdx.x;
    const void* src; u16* dst; int Nc, mid;
    if (id < 128)       { src = Wq; dst = W1T;               Nc = 128;  mid = id; }
    else if (id < 256)  { src = Wk; dst = W1T + 128 * 1024;  Nc = 128;  mid = id - 128; }
    else if (id < 1280) { src = Wv; dst = W1T + 256 * 1024;  Nc = 1024; mid = id - 256; }
    else                { src = Op; dst = OpT;               Nc = 1024; mid = id - 1280; }
    int kt = mid & 31, nt = mid >> 5;
    __shared__ u16 tile[32][33];
    int x = threadIdx.x & 31, y0 = threadIdx.x >> 5;
#pragma unroll
    for (int yy = 0; yy < 4; ++yy) {
        int y = y0 * 4 + yy;
        tile[y][x] = rd_elem(src, (kt * 32 + y) * Nc + nt * 32 + x, fp32);
    }
    __syncthreads();
#pragma unroll
    for (int yy = 0; yy < 4; ++yy) {
        int y = y0 * 4 + yy;
        dst[(nt * 32 + y) * 1024 + kt * 32 + x] = tile[x][y];
    }
}

// ---------------------------------------------------------------------------
// Partial Kv/Ksum over 256-row chunks, NO max-shift: Kv/Ksum is exactly
// invariant to the max subtraction (it cancels in the ratio); K = X@Wk has
// unit-variance entries (|K| <~ 5, e^K <= ~150, sums ~1e4) so fp32 is safe
// without it. Removes the maxpart kernel + the per-block prologue reduce.
// Mask is read directly from the input (dual-dtype) -- convert_mask deleted.
// Grid is XCD-chunked (T1): the 16 h-blocks sharing a (b,chunk) row-range are
// consecutive in tile space -> same XCD -> V's 256B lines fetched into ONE L2
// (disjoint 128B slices per h previously straddled XCDs).
// ---------------------------------------------------------------------------
__global__ __launch_bounds__(256) void kvpart_kernel(const u16* __restrict__ QKV,
                                                     const void* __restrict__ mask,
                                                     const int* __restrict__ flags,
                                                     float* __restrict__ Kvp,
                                                     float* __restrict__ Ksp) {
    // XCD-chunked swizzle over 2048 blocks: t = xcd*256 + idx
    int t_ = (blockIdx.x & 7) * 256 + (blockIdx.x >> 3);
    int h = t_ & 15;
    int bc = t_ >> 4;                 // b*32 + chunk
    int chunk = bc & 31, b = bc >> 5;
    int w = threadIdx.x >> 6, lane = threadIdx.x & 63;
    int fp32m = flags[0];

    float kv[8] = {0, 0, 0, 0, 0, 0, 0, 0};
    float ks[8] = {0, 0, 0, 0, 0, 0, 0, 0};
    int t0 = chunk * 256;
    for (int i = 0; i < 64; ++i) {
        int t = t0 + w + i * 4;
        int m = b * 8192 + t;
        const u16* row = QKV + (size_t)m * 1280;
        float v = bf2f(row[256 + h * 64 + lane]);
        uint4 kq = *(const uint4*)(row + 128 + h * 8);
        float msk = fp32m ? ((const float*)mask)[m] : bf2f(((const u16*)mask)[m]);
        float vm = v * msk;
        float kf[8];
        kf[0] = __builtin_bit_cast(float, kq.x << 16);
        kf[1] = __builtin_bit_cast(float, kq.x & 0xffff0000u);
        kf[2] = __builtin_bit_cast(float, kq.y << 16);
        kf[3] = __builtin_bit_cast(float, kq.y & 0xffff0000u);
        kf[4] = __builtin_bit_cast(float, kq.z << 16);
        kf[5] = __builtin_bit_cast(float, kq.z & 0xffff0000u);
        kf[6] = __builtin_bit_cast(float, kq.w << 16);
        kf[7] = __builtin_bit_cast(float, kq.w & 0xffff0000u);
#pragma unroll
        for (int l = 0; l < 8; ++l) {
            float e = __expf(kf[l]) * msk;           // exp(K)*mask (no shift)
            kv[l] += e * vm;                         // * (V*mask)
            ks[l] += e;
        }
    }
    __shared__ float red[4][8][64];
    __shared__ float redks[4][8];
#pragma unroll
    for (int l = 0; l < 8; ++l) red[w][l][lane] = kv[l];
    if (lane == 0) {
#pragma unroll
        for (int l = 0; l < 8; ++l) redks[w][l] = ks[l];
    }
    __syncthreads();
    int tid = threadIdx.x;
    int obid = (b * 16 + h) * 32 + chunk;            // layout expected by kvreduce
    for (int c = tid; c < 512; c += 256) {
        int l = c >> 6, d = c & 63;
        Kvp[obid * 512 + c] = red[0][l][d] + red[1][l][d] + red[2][l][d] + red[3][l][d];
    }
    if (tid < 8) Ksp[obid * 8 + tid] = redks[0][tid] + redks[1][tid] + redks[2][tid] + redks[3][tid];
}

__global__ void kvreduce_kernel(const float* __restrict__ Kvp, const float* __restrict__ Ksp,
                                float* __restrict__ Kv) {
    int bh = blockIdx.x;             // 64
    int tid = threadIdx.x;           // 512 = l*64+d
    int l = tid >> 6;
    float s = 0.f, ks = 0.f;
    for (int c = 0; c < 32; ++c) {
        s += Kvp[(bh * 32 + c) * 512 + tid];
        ks += Ksp[(bh * 32 + c) * 8 + l];
    }
    Kv[bh * 512 + tid] = s / ks;
}

// ---------------------------------------------------------------------------
// y[m, h*64+d] = softmax_l(Q[m,h,:]) @ Kv[b,h,l,d]; in-place over V region.
// 2048 blocks (16 rows/block): 8 blocks/CU for latency hiding.
// ---------------------------------------------------------------------------
__global__ __launch_bounds__(256) void y_kernel(u16* __restrict__ QKV,
                                                const float* __restrict__ Kv) {
    int bid = blockIdx.x;            // b*512 + chunk(16 rows)
    int b = bid >> 9, chunk = bid & 511;
    int w = threadIdx.x >> 6, lane = threadIdx.x & 63;
    int hh = w & 1;
    int rp = w >> 1;
    int hloc = lane >> 3;
    int h = hh * 8 + hloc;
    int dg = lane & 7;

    float4 kva[8], kvb[8];
    const float* kvp = Kv + (b * 16 + h) * 512 + dg * 8;
#pragma unroll
    for (int l = 0; l < 8; ++l) {
        kva[l] = *(const float4*)(kvp + l * 64);
        kvb[l] = *(const float4*)(kvp + l * 64 + 4);
    }
    int lgrp = lane & 56;
    for (int i = 0; i < 8; ++i) {
        int t = chunk * 16 + i * 2 + rp;
        int m = b * 8192 + t;
        u16* row = QKV + (size_t)m * 1280;
        float qv = bf2f(row[hh * 64 + lane]);
        float qm = qv;
        qm = fmaxf(qm, __shfl_xor(qm, 1));
        qm = fmaxf(qm, __shfl_xor(qm, 2));
        qm = fmaxf(qm, __shfl_xor(qm, 4));
        float e = __expf(qv - qm);
        float s = e;
        s += __shfl_xor(s, 1);
        s += __shfl_xor(s, 2);
        s += __shfl_xor(s, 4);
        float qs = e / s;
        float4 a0 = {0.f, 0.f, 0.f, 0.f}, a1 = {0.f, 0.f, 0.f, 0.f};
#pragma unroll
        for (int l = 0; l < 8; ++l) {
            float ql = __shfl(qs, lgrp + l);
            a0.x += ql * kva[l].x; a0.y += ql * kva[l].y;
            a0.z += ql * kva[l].z; a0.w += ql * kva[l].w;
            a1.x += ql * kvb[l].x; a1.y += ql * kvb[l].y;
            a1.z += ql * kvb[l].z; a1.w += ql * kvb[l].w;
        }
        uint4 o;
        o.x = pack2(a0.x, a0.y);
        o.y = pack2(a0.z, a0.w);
        o.z = pack2(a1.x, a1.y);
        o.w = pack2(a1.z, a1.w);
        *(uint4*)(row + 256 + h * 64 + dg * 8) = o;
    }
}

// ---------------------------------------------------------------------------
// Workspace layout (bytes).
// ---------------------------------------------------------------------------
#define OFF_FLAG ((size_t)0)                        // 2 ints
#define OFF_W1T  ((size_t)1024)                     // 1280*1024*2 = 2,621,440
#define OFF_OPT  ((size_t)2622464)                  // 1024*1024*2 = 2,097,152
#define OFF_KVP  ((size_t)4787200)                  // 2048*512*4 = 4,194,304
#define OFF_KSP  ((size_t)8981504)                  // 2048*8*4 = 65,536
#define OFF_KV   ((size_t)9047040)                  // 64*512*4 = 131,072
#define OFF_XC   ((size_t)9309184)                  // 33554432*2 = 67,108,864
#define OFF_QKV  ((size_t)76418048)                 // 32768*1280*2 = 83,886,080
// total = 160,304,128 bytes

extern "C" void kernel_launch(void* const* d_in, const int* in_sizes, int n_in,
                              void* d_out, int out_size, void* d_ws, size_t ws_size,
                              hipStream_t stream) {
    const u16* X   = (const u16*)d_in[0];
    const void* msk = d_in[1];
    const void* Wk  = d_in[2];
    const void* Wq  = d_in[3];
    const void* Wv  = d_in[4];
    const void* Op  = d_in[5];

    char* ws = (char*)d_ws;
    int*   FLAGS = (int*)(ws + OFF_FLAG);
    u16*   W1T  = (u16*)(ws + OFF_W1T);
    u16*   OPT  = (u16*)(ws + OFF_OPT);
    float* KVP  = (float*)(ws + OFF_KVP);
    float* KSP  = (float*)(ws + OFF_KSP);
    float* KV   = (float*)(ws + OFF_KV);
    u16*   XC   = (u16*)(ws + OFF_XC);
    u16*   QKV  = (u16*)(ws + OFF_QKV);

    // 0) detect input dtype (flags[0]=1 -> fp32), flags[1]=0 always
    detect_kernel<<<1, 256, 0, stream>>>(X, FLAGS);
    // 0b) canonicalize X (no-op if bf16); mask is consumed raw by kvpart
    convert_x<<<16384, 256, 0, stream>>>((const float*)d_in[0], XC, FLAGS, 33554432);
    // 1) transpose weights to (N,K) bf16 (dual-dtype reads)
    transpose_k<<<2304, 256, 0, stream>>>(Wq, Wk, Wv, Op, W1T, OPT, FLAGS);
    // 2) fused QKV projection: QKV[m,0:128)=Q, [128:256)=K, [256:1280)=V
    gemm_bt<<<2560, 256, 0, stream>>>(X, XC, 1024, W1T, 1024, QKV, 1280, 256, 1024,
                                      FLAGS, FLAGS + 1);
    // 3) Kv state + Ksum (no max pass -- it cancels in Kv/Ksum)
    kvpart_kernel<<<2048, 256, 0, stream>>>(QKV, msk, FLAGS, KVP, KSP);
    kvreduce_kernel<<<64, 512, 0, stream>>>(KVP, KSP, KV);
    // 4) y = softmax(Q) @ Kv, in-place over V region
    y_kernel<<<2048, 256, 0, stream>>>(QKV, KV);
    // 5) out = y @ o_proj (output dtype per detected flag)
    gemm_bt<<<2048, 256, 0, stream>>>(QKV + 256, QKV + 256, 1280, OPT, 1024,
                                      d_out, 1024, 256, 1024, FLAGS + 1, FLAGS);
}

// Round 11
// 533.897 us; speedup vs baseline: 6.7970x; 1.0750x over previous
//
#include <hip/hip_runtime.h>
#include <hip/hip_bf16.h>

typedef unsigned short u16;
typedef unsigned int   u32;

typedef __attribute__((ext_vector_type(8))) short short8;
typedef __attribute__((ext_vector_type(4))) float f32x4;

typedef const __attribute__((address_space(1))) void g_void;
typedef __attribute__((address_space(3))) void l_void;

__device__ __forceinline__ float bf2f(u16 u) {
    u32 x = ((u32)u) << 16;
    return __builtin_bit_cast(float, x);
}
__device__ __forceinline__ u16 f2bf(float f) {
    u32 u = __builtin_bit_cast(u32, f);
    u32 r = (u + 0x7FFFu + ((u >> 16) & 1u)) >> 16;
    return (u16)r;
}
__device__ __forceinline__ u32 pack2(float a, float b) {
    return (u32)f2bf(a) | ((u32)f2bf(b) << 16);
}

// ---------------------------------------------------------------------------
// Dtype detector: reads first 16384 u16 words of X. bf16 data -> ~100% sane
// exponent fields; fp32 data reinterpreted as u16 -> ~57%. flags[0]=1 => fp32.
// flags[1] is a guaranteed-zero word used by consumers needing "always bf16".
// ---------------------------------------------------------------------------
__global__ void detect_kernel(const u16* __restrict__ X, int* __restrict__ flags) {
    __shared__ int cnt[256];
    int c = 0;
    for (int i = threadIdx.x; i < 16384; i += 256) {
        u16 v = X[i];
        int e = (v >> 7) & 0xFF;
        c += (e >= 104 && e <= 140) ? 1 : 0;
    }
    cnt[threadIdx.x] = c;
    __syncthreads();
    for (int s = 128; s > 0; s >>= 1) {
        if (threadIdx.x < s) cnt[threadIdx.x] += cnt[threadIdx.x + s];
        __syncthreads();
    }
    if (threadIdx.x == 0) {
        flags[0] = (cnt[0] < 14746) ? 1 : 0;   // <90% sane => fp32
        flags[1] = 0;
    }
}

// X canonicalization: only does work when input is fp32 (copies to bf16 XC).
__global__ __launch_bounds__(256) void convert_x(const float* __restrict__ Xf,
                                                 u16* __restrict__ XC,
                                                 const int* __restrict__ flags, int n) {
    if (flags[0] == 0) return;
    int i = (blockIdx.x * 256 + threadIdx.x) * 8;
    if (i >= n) return;
    float4 a = *(const float4*)(Xf + i);
    float4 b = *(const float4*)(Xf + i + 4);
    uint4 o;
    o.x = pack2(a.x, a.y); o.y = pack2(a.z, a.w);
    o.z = pack2(b.x, b.y); o.w = pack2(b.z, b.w);
    *(uint4*)(XC + i) = o;
}

// ---------------------------------------------------------------------------
// GEMM: C(MxN, ldc) = A(MxK, bf16, lda) * Bt(NxK, bf16, ldb)^T
// 128x128 tile, BK=32, 4 waves (2x2), 16x16x32 bf16 MFMA.
// R8: XCD-chunked blockIdx swizzle (T1) -> FETCH 290->79 MB (verified R9).
// R10: 2-PHASE DOUBLE-BUFFER with counted vmcnt (T3/T4). The old loop did
// gload_lds -> __syncthreads (implicit vmcnt(0) drain) -> compute: every
// K-iter ate the full staging latency (MfmaUtil 27%, HBM 15% - neither
// pipe busy). Now tile t+1 stages into the other 16KB buffer while tile t
// computes; s_waitcnt vmcnt(4) waits only the OLDER 4 loads; raw s_barrier
// (no drain) + sched_barrier(0) fences (rule #18).
// Epilogue: stride-132 bank pad (conflicts 3.28M -> 0, verified R8);
// fb aliases the dead staging buffers.
// ---------------------------------------------------------------------------
__global__ __launch_bounds__(256) void gemm_bt(
    const u16* __restrict__ A0, const u16* __restrict__ A1, int lda,
    const u16* __restrict__ Bt, int ldb,
    void* __restrict__ C, int ldc,
    int Mtiles, int K,
    const int* __restrict__ aselp, const int* __restrict__ ofp) {
    __shared__ char smem[32768];     // 2 x 16KB staging buffers

    const u16* A = aselp[0] ? A1 : A0;

    const int tid = threadIdx.x;
    const int w = tid >> 6, lane = tid & 63;
    const int Ntiles = gridDim.x / Mtiles;
    // XCD-chunked swizzle: xcd = bid & 7 owns tiles [xcd*q8, (xcd+1)*q8)
    const int q8 = gridDim.x >> 3;
    const int t  = (blockIdx.x & 7) * q8 + (blockIdx.x >> 3);
    const int mt = t / Ntiles;
    const int nt = t % Ntiles;
    const int m0 = mt << 7, n0 = nt << 7;
    const int wm = w >> 1, wn = w & 1;

    f32x4 acc[4][4] = {};

    // staging: row rr = w*16 + lane/4 (plus +64 for second store),
    // LDS slot s = lane&3 holds global chunk cg = s ^ swz(row), swz(r)=(r>>1)&3
    const int rr = w * 16 + (lane >> 2);
    const int cg = (lane & 3) ^ ((lane >> 3) & 3);

    const u16* gA0 = A + (m0 + rr) * lda + cg * 8;
    const u16* gA1 = A + (m0 + rr + 64) * lda + cg * 8;
    const u16* gB0 = Bt + (n0 + rr) * ldb + cg * 8;
    const u16* gB1 = Bt + (n0 + rr + 64) * ldb + cg * 8;

    // per-buffer LDS staging offsets (linear in lane)
    const int st0 = w * 1024 + lane * 16;

    // fragment reads: row = wm*64 + mi*16 + (lane&15), chunk q = lane>>4,
    // slot = q ^ ((lane>>1)&3)
    const int fr_a = (wm << 6) + (lane & 15);
    const int fr_b = (wn << 6) + (lane & 15);
    const int sl = (lane >> 4) ^ ((lane >> 1) & 3);
    const int offA = fr_a * 64 + sl * 16;
    const int offB = 8192 + fr_b * 64 + sl * 16;

#define STAGE(buf, kt) do {                                                        \
        char* sb_ = smem + (buf) * 16384;                                          \
        __builtin_amdgcn_global_load_lds((g_void*)(gA0 + (kt)),                    \
            (l_void*)(sb_ + st0), 16, 0, 0);                                       \
        __builtin_amdgcn_global_load_lds((g_void*)(gA1 + (kt)),                    \
            (l_void*)(sb_ + 4096 + st0), 16, 0, 0);                                \
        __builtin_amdgcn_global_load_lds((g_void*)(gB0 + (kt)),                    \
            (l_void*)(sb_ + 8192 + st0), 16, 0, 0);                                \
        __builtin_amdgcn_global_load_lds((g_void*)(gB1 + (kt)),                    \
            (l_void*)(sb_ + 12288 + st0), 16, 0, 0);                               \
    } while (0)

#define COMPUTE(buf) do {                                                          \
        const char* cb_ = smem + (buf) * 16384;                                    \
        short8 af[4], bfv[4];                                                      \
        _Pragma("unroll")                                                          \
        for (int i = 0; i < 4; ++i) {                                              \
            af[i]  = *(const short8*)(cb_ + offA + i * 1024);                      \
            bfv[i] = *(const short8*)(cb_ + offB + i * 1024);                      \
        }                                                                          \
        _Pragma("unroll")                                                          \
        for (int mi = 0; mi < 4; ++mi)                                             \
            _Pragma("unroll")                                                      \
            for (int ni = 0; ni < 4; ++ni)                                         \
                acc[mi][ni] = __builtin_amdgcn_mfma_f32_16x16x32_bf16(             \
                    af[mi], bfv[ni], acc[mi][ni], 0, 0, 0);                        \
    } while (0)

    STAGE(0, 0);
    int cur = 0;
    for (int kt = 32; kt < K; kt += 32) {
        STAGE(cur ^ 1, kt);                          // prefetch next tile
        asm volatile("s_waitcnt vmcnt(4)" ::: "memory");   // older 4 done
        __builtin_amdgcn_s_barrier();
        __builtin_amdgcn_sched_barrier(0);
        COMPUTE(cur);
        __builtin_amdgcn_sched_barrier(0);
        __builtin_amdgcn_s_barrier();                // all waves done reading cur
        cur ^= 1;
    }
    asm volatile("s_waitcnt vmcnt(0)" ::: "memory");
    __builtin_amdgcn_s_barrier();
    __builtin_amdgcn_sched_barrier(0);
    COMPUTE(cur);
    __syncthreads();                                 // full drain before fb reuse

#undef STAGE
#undef COMPUTE

    // epilogue: repack 32-row strips through LDS (stride 132 = bank pad);
    // fully unrolled so every acc index is compile-time constant (rule #20).
    const int out_fp32 = ofp[0];
    float* fb = (float*)smem;
    const int lrow = tid >> 3, cgp = tid & 7;
#pragma unroll
    for (int mi = 0; mi < 4; ++mi) {
#pragma unroll
        for (int ni = 0; ni < 4; ++ni) {
#pragma unroll
            for (int r = 0; r < 4; ++r) {
                int lr = wm * 16 + ((lane >> 4) << 2) + r;
                int lc = wn * 64 + ni * 16 + (lane & 15);
                fb[lr * 132 + lc] = acc[mi][ni][r];
            }
        }
        __syncthreads();
        int grow = (lrow < 16) ? (mi * 16 + lrow) : (48 + mi * 16 + lrow);
        const float* srcp = fb + lrow * 132 + cgp * 16;
        if (out_fp32) {
            float4* dst = (float4*)((float*)C + (size_t)(m0 + grow) * ldc + n0 + cgp * 16);
            dst[0] = make_float4(srcp[0], srcp[1], srcp[2], srcp[3]);
            dst[1] = make_float4(srcp[4], srcp[5], srcp[6], srcp[7]);
            dst[2] = make_float4(srcp[8], srcp[9], srcp[10], srcp[11]);
            dst[3] = make_float4(srcp[12], srcp[13], srcp[14], srcp[15]);
        } else {
            u32 o0 = pack2(srcp[0], srcp[1]);
            u32 o1 = pack2(srcp[2], srcp[3]);
            u32 o2 = pack2(srcp[4], srcp[5]);
            u32 o3 = pack2(srcp[6], srcp[7]);
            u32 o4 = pack2(srcp[8], srcp[9]);
            u32 o5 = pack2(srcp[10], srcp[11]);
            u32 o6 = pack2(srcp[12], srcp[13]);
            u32 o7 = pack2(srcp[14], srcp[15]);
            uint4* dst = (uint4*)((u16*)C + (size_t)(m0 + grow) * ldc + n0 + cgp * 16);
            dst[0] = make_uint4(o0, o1, o2, o3);
            dst[1] = make_uint4(o4, o5, o6, o7);
        }
        __syncthreads();
    }
}

// ---------------------------------------------------------------------------
// Transpose weights into (N,K) row-major bf16, dual-dtype source reads.
// W1T rows [0,128)=Wq^T, [128,256)=Wk^T, [256,1280)=Wv^T; OpT = o_proj^T.
// ---------------------------------------------------------------------------
__device__ __forceinline__ u16 rd_elem(const void* s, int idx, int fp32) {
    return fp32 ? f2bf(((const float*)s)[idx]) : ((const u16*)s)[idx];
}

__global__ void transpose_k(const void* __restrict__ Wq, const void* __restrict__ Wk,
                            const void* __restrict__ Wv, const void* __restrict__ Op,
                            u16* __restrict__ W1T, u16* __restrict__ OpT,
                            const int* __restrict__ flags) {
    int fp32 = flags[0];
    int id = blockIdx.x;
    const void* src; u16* dst; int Nc, mid;
    if (id < 128)       { src = Wq; dst = W1T;               Nc = 128;  mid = id; }
    else if (id < 256)  { src = Wk; dst = W1T + 128 * 1024;  Nc = 128;  mid = id - 128; }
    else if (id < 1280) { src = Wv; dst = W1T + 256 * 1024;  Nc = 1024; mid = id - 256; }
    else                { src = Op; dst = OpT;               Nc = 1024; mid = id - 1280; }
    int kt = mid & 31, nt = mid >> 5;
    __shared__ u16 tile[32][33];
    int x = threadIdx.x & 31, y0 = threadIdx.x >> 5;
#pragma unroll
    for (int yy = 0; yy < 4; ++yy) {
        int y = y0 * 4 + yy;
        tile[y][x] = rd_elem(src, (kt * 32 + y) * Nc + nt * 32 + x, fp32);
    }
    __syncthreads();
#pragma unroll
    for (int yy = 0; yy < 4; ++yy) {
        int y = y0 * 4 + yy;
        dst[(nt * 32 + y) * 1024 + kt * 32 + x] = tile[x][y];
    }
}

// ---------------------------------------------------------------------------
// Partial Kv/Ksum over 256-row chunks, NO max-shift (cancels in Kv/Ksum;
// |K| <~ 5 so fp32 exp is safe). Mask read dual-dtype from the raw input.
// Grid XCD-chunked (T1).
// ---------------------------------------------------------------------------
__global__ __launch_bounds__(256) void kvpart_kernel(const u16* __restrict__ QKV,
                                                     const void* __restrict__ mask,
                                                     const int* __restrict__ flags,
                                                     float* __restrict__ Kvp,
                                                     float* __restrict__ Ksp) {
    // XCD-chunked swizzle over 2048 blocks: t = xcd*256 + idx
    int t_ = (blockIdx.x & 7) * 256 + (blockIdx.x >> 3);
    int h = t_ & 15;
    int bc = t_ >> 4;                 // b*32 + chunk
    int chunk = bc & 31, b = bc >> 5;
    int w = threadIdx.x >> 6, lane = threadIdx.x & 63;
    int fp32m = flags[0];

    float kv[8] = {0, 0, 0, 0, 0, 0, 0, 0};
    float ks[8] = {0, 0, 0, 0, 0, 0, 0, 0};
    int t0 = chunk * 256;
    for (int i = 0; i < 64; ++i) {
        int t = t0 + w + i * 4;
        int m = b * 8192 + t;
        const u16* row = QKV + (size_t)m * 1280;
        float v = bf2f(row[256 + h * 64 + lane]);
        uint4 kq = *(const uint4*)(row + 128 + h * 8);
        float msk = fp32m ? ((const float*)mask)[m] : bf2f(((const u16*)mask)[m]);
        float vm = v * msk;
        float kf[8];
        kf[0] = __builtin_bit_cast(float, kq.x << 16);
        kf[1] = __builtin_bit_cast(float, kq.x & 0xffff0000u);
        kf[2] = __builtin_bit_cast(float, kq.y << 16);
        kf[3] = __builtin_bit_cast(float, kq.y & 0xffff0000u);
        kf[4] = __builtin_bit_cast(float, kq.z << 16);
        kf[5] = __builtin_bit_cast(float, kq.z & 0xffff0000u);
        kf[6] = __builtin_bit_cast(float, kq.w << 16);
        kf[7] = __builtin_bit_cast(float, kq.w & 0xffff0000u);
#pragma unroll
        for (int l = 0; l < 8; ++l) {
            float e = __expf(kf[l]) * msk;           // exp(K)*mask (no shift)
            kv[l] += e * vm;                         // * (V*mask)
            ks[l] += e;
        }
    }
    __shared__ float red[4][8][64];
    __shared__ float redks[4][8];
#pragma unroll
    for (int l = 0; l < 8; ++l) red[w][l][lane] = kv[l];
    if (lane == 0) {
#pragma unroll
        for (int l = 0; l < 8; ++l) redks[w][l] = ks[l];
    }
    __syncthreads();
    int tid = threadIdx.x;
    int obid = (b * 16 + h) * 32 + chunk;            // layout expected by kvreduce
    for (int c = tid; c < 512; c += 256) {
        int l = c >> 6, d = c & 63;
        Kvp[obid * 512 + c] = red[0][l][d] + red[1][l][d] + red[2][l][d] + red[3][l][d];
    }
    if (tid < 8) Ksp[obid * 8 + tid] = redks[0][tid] + redks[1][tid] + redks[2][tid] + redks[3][tid];
}

// 256 blocks x 128 threads (was 64x512 = 0.25 blocks/CU, pure-latency).
__global__ void kvreduce_kernel(const float* __restrict__ Kvp, const float* __restrict__ Ksp,
                                float* __restrict__ Kv) {
    int bh = blockIdx.x >> 2;        // 64 bh values
    int seg = blockIdx.x & 3;
    int c0 = seg * 128 + threadIdx.x;   // element in [0,512)
    int l = c0 >> 6;
    float s = 0.f, ks = 0.f;
    for (int c = 0; c < 32; ++c) {
        s += Kvp[(bh * 32 + c) * 512 + c0];
        ks += Ksp[(bh * 32 + c) * 8 + l];
    }
    Kv[bh * 512 + c0] = s / ks;
}

// ---------------------------------------------------------------------------
// y[m, h*64+d] = softmax_l(Q[m,h,:]) @ Kv[b,h,l,d]; in-place over V region.
// 2048 blocks (16 rows/block): 8 blocks/CU for latency hiding.
// ---------------------------------------------------------------------------
__global__ __launch_bounds__(256) void y_kernel(u16* __restrict__ QKV,
                                                const float* __restrict__ Kv) {
    int bid = blockIdx.x;            // b*512 + chunk(16 rows)
    int b = bid >> 9, chunk = bid & 511;
    int w = threadIdx.x >> 6, lane = threadIdx.x & 63;
    int hh = w & 1;
    int rp = w >> 1;
    int hloc = lane >> 3;
    int h = hh * 8 + hloc;
    int dg = lane & 7;

    float4 kva[8], kvb[8];
    const float* kvp = Kv + (b * 16 + h) * 512 + dg * 8;
#pragma unroll
    for (int l = 0; l < 8; ++l) {
        kva[l] = *(const float4*)(kvp + l * 64);
        kvb[l] = *(const float4*)(kvp + l * 64 + 4);
    }
    int lgrp = lane & 56;
    for (int i = 0; i < 8; ++i) {
        int t = chunk * 16 + i * 2 + rp;
        int m = b * 8192 + t;
        u16* row = QKV + (size_t)m * 1280;
        float qv = bf2f(row[hh * 64 + lane]);
        float qm = qv;
        qm = fmaxf(qm, __shfl_xor(qm, 1));
        qm = fmaxf(qm, __shfl_xor(qm, 2));
        qm = fmaxf(qm, __shfl_xor(qm, 4));
        float e = __expf(qv - qm);
        float s = e;
        s += __shfl_xor(s, 1);
        s += __shfl_xor(s, 2);
        s += __shfl_xor(s, 4);
        float qs = e / s;
        float4 a0 = {0.f, 0.f, 0.f, 0.f}, a1 = {0.f, 0.f, 0.f, 0.f};
#pragma unroll
        for (int l = 0; l < 8; ++l) {
            float ql = __shfl(qs, lgrp + l);
            a0.x += ql * kva[l].x; a0.y += ql * kva[l].y;
            a0.z += ql * kva[l].z; a0.w += ql * kva[l].w;
            a1.x += ql * kvb[l].x; a1.y += ql * kvb[l].y;
            a1.z += ql * kvb[l].z; a1.w += ql * kvb[l].w;
        }
        uint4 o;
        o.x = pack2(a0.x, a0.y);
        o.y = pack2(a0.z, a0.w);
        o.z = pack2(a1.x, a1.y);
        o.w = pack2(a1.z, a1.w);
        *(uint4*)(row + 256 + h * 64 + dg * 8) = o;
    }
}

// ---------------------------------------------------------------------------
// Workspace layout (bytes).
// ---------------------------------------------------------------------------
#define OFF_FLAG ((size_t)0)                        // 2 ints
#define OFF_W1T  ((size_t)1024)                     // 1280*1024*2 = 2,621,440
#define OFF_OPT  ((size_t)2622464)                  // 1024*1024*2 = 2,097,152
#define OFF_KVP  ((size_t)4787200)                  // 2048*512*4 = 4,194,304
#define OFF_KSP  ((size_t)8981504)                  // 2048*8*4 = 65,536
#define OFF_KV   ((size_t)9047040)                  // 64*512*4 = 131,072
#define OFF_XC   ((size_t)9309184)                  // 33554432*2 = 67,108,864
#define OFF_QKV  ((size_t)76418048)                 // 32768*1280*2 = 83,886,080
// total = 160,304,128 bytes

extern "C" void kernel_launch(void* const* d_in, const int* in_sizes, int n_in,
                              void* d_out, int out_size, void* d_ws, size_t ws_size,
                              hipStream_t stream) {
    const u16* X   = (const u16*)d_in[0];
    const void* msk = d_in[1];
    const void* Wk  = d_in[2];
    const void* Wq  = d_in[3];
    const void* Wv  = d_in[4];
    const void* Op  = d_in[5];

    char* ws = (char*)d_ws;
    int*   FLAGS = (int*)(ws + OFF_FLAG);
    u16*   W1T  = (u16*)(ws + OFF_W1T);
    u16*   OPT  = (u16*)(ws + OFF_OPT);
    float* KVP  = (float*)(ws + OFF_KVP);
    float* KSP  = (float*)(ws + OFF_KSP);
    float* KV   = (float*)(ws + OFF_KV);
    u16*   XC   = (u16*)(ws + OFF_XC);
    u16*   QKV  = (u16*)(ws + OFF_QKV);

    // 0) detect input dtype (flags[0]=1 -> fp32), flags[1]=0 always
    detect_kernel<<<1, 256, 0, stream>>>(X, FLAGS);
    // 0b) canonicalize X (no-op if bf16); mask is consumed raw by kvpart
    convert_x<<<16384, 256, 0, stream>>>((const float*)d_in[0], XC, FLAGS, 33554432);
    // 1) transpose weights to (N,K) bf16 (dual-dtype reads)
    transpose_k<<<2304, 256, 0, stream>>>(Wq, Wk, Wv, Op, W1T, OPT, FLAGS);
    // 2) fused QKV projection: QKV[m,0:128)=Q, [128:256)=K, [256:1280)=V
    gemm_bt<<<2560, 256, 0, stream>>>(X, XC, 1024, W1T, 1024, QKV, 1280, 256, 1024,
                                      FLAGS, FLAGS + 1);
    // 3) Kv state + Ksum (no max pass -- it cancels in Kv/Ksum)
    kvpart_kernel<<<2048, 256, 0, stream>>>(QKV, msk, FLAGS, KVP, KSP);
    kvreduce_kernel<<<256, 128, 0, stream>>>(KVP, KSP, KV);
    // 4) y = softmax(Q) @ Kv, in-place over V region
    y_kernel<<<2048, 256, 0, stream>>>(QKV, KV);
    // 5) out = y @ o_proj (output dtype per detected flag)
    gemm_bt<<<2048, 256, 0, stream>>>(QKV + 256, QKV + 256, 1280, OPT, 1024,
                                      d_out, 1024, 256, 1024, FLAGS + 1, FLAGS);
}

// Round 13
// 532.664 us; speedup vs baseline: 6.8127x; 1.0023x over previous
//
#include <hip/hip_runtime.h>
#include <hip/hip_bf16.h>

typedef unsigned short u16;
typedef unsigned int   u32;

typedef __attribute__((ext_vector_type(8))) short short8;
typedef __attribute__((ext_vector_type(4))) float f32x4;

typedef const __attribute__((address_space(1))) void g_void;
typedef __attribute__((address_space(3))) void l_void;

__device__ __forceinline__ float bf2f(u16 u) {
    u32 x = ((u32)u) << 16;
    return __builtin_bit_cast(float, x);
}
__device__ __forceinline__ u16 f2bf(float f) {
    u32 u = __builtin_bit_cast(u32, f);
    u32 r = (u + 0x7FFFu + ((u >> 16) & 1u)) >> 16;
    return (u16)r;
}
__device__ __forceinline__ u32 pack2(float a, float b) {
    return (u32)f2bf(a) | ((u32)f2bf(b) << 16);
}

// ---------------------------------------------------------------------------
// Dtype detector: reads first 16384 u16 words of X. bf16 data -> ~100% sane
// exponent fields; fp32 data reinterpreted as u16 -> ~57%. flags[0]=1 => fp32.
// flags[1] is a guaranteed-zero word used by consumers needing "always bf16".
// ---------------------------------------------------------------------------
__global__ void detect_kernel(const u16* __restrict__ X, int* __restrict__ flags) {
    __shared__ int cnt[256];
    int c = 0;
    for (int i = threadIdx.x; i < 16384; i += 256) {
        u16 v = X[i];
        int e = (v >> 7) & 0xFF;
        c += (e >= 104 && e <= 140) ? 1 : 0;
    }
    cnt[threadIdx.x] = c;
    __syncthreads();
    for (int s = 128; s > 0; s >>= 1) {
        if (threadIdx.x < s) cnt[threadIdx.x] += cnt[threadIdx.x + s];
        __syncthreads();
    }
    if (threadIdx.x == 0) {
        flags[0] = (cnt[0] < 14746) ? 1 : 0;   // <90% sane => fp32
        flags[1] = 0;
    }
}

__device__ __forceinline__ u16 rd_elem(const void* s, int idx, int fp32) {
    return fp32 ? f2bf(((const float*)s)[idx]) : ((const u16*)s)[idx];
}

// ---------------------------------------------------------------------------
// Fused preprocessing (one launch):
//  blocks [0,16384): X canonicalization (fp32 -> bf16 XC; no-op if bf16)
//  blocks [16384,18688): weight transposes into (N,K) bf16
// Both depend only on flags -> independent, share the dispatch.
// ---------------------------------------------------------------------------
__global__ __launch_bounds__(256) void prep_kernel(
    const float* __restrict__ Xf, u16* __restrict__ XC,
    const void* __restrict__ Wq, const void* __restrict__ Wk,
    const void* __restrict__ Wv, const void* __restrict__ Op,
    u16* __restrict__ W1T, u16* __restrict__ OpT,
    const int* __restrict__ flags) {
    int fp32 = flags[0];
    if (blockIdx.x < 16384) {
        if (fp32 == 0) return;
        int i = (blockIdx.x * 256 + threadIdx.x) * 8;
        float4 a = *(const float4*)(Xf + i);
        float4 b = *(const float4*)(Xf + i + 4);
        uint4 o;
        o.x = pack2(a.x, a.y); o.y = pack2(a.z, a.w);
        o.z = pack2(b.x, b.y); o.w = pack2(b.z, b.w);
        *(uint4*)(XC + i) = o;
        return;
    }
    int id = blockIdx.x - 16384;
    const void* src; u16* dst; int Nc, mid;
    if (id < 128)       { src = Wq; dst = W1T;               Nc = 128;  mid = id; }
    else if (id < 256)  { src = Wk; dst = W1T + 128 * 1024;  Nc = 128;  mid = id - 128; }
    else if (id < 1280) { src = Wv; dst = W1T + 256 * 1024;  Nc = 1024; mid = id - 256; }
    else                { src = Op; dst = OpT;               Nc = 1024; mid = id - 1280; }
    int kt = mid & 31, nt = mid >> 5;
    __shared__ u16 tile[32][33];
    int x = threadIdx.x & 31, y0 = threadIdx.x >> 5;
#pragma unroll
    for (int yy = 0; yy < 4; ++yy) {
        int y = y0 * 4 + yy;
        tile[y][x] = rd_elem(src, (kt * 32 + y) * Nc + nt * 32 + x, fp32);
    }
    __syncthreads();
#pragma unroll
    for (int yy = 0; yy < 4; ++yy) {
        int y = y0 * 4 + yy;
        dst[(nt * 32 + y) * 1024 + kt * 32 + x] = tile[x][y];
    }
}

// ---------------------------------------------------------------------------
// GEMM: C(MxN, ldc) = A(MxK, bf16, lda) * Bt(NxK, bf16, ldb)^T
// 128x128 tile, BK=32, 4 waves (2x2), 16x16x32 bf16 MFMA.
// R8: XCD-chunked blockIdx swizzle (T1) -> FETCH 290->79 MB (verified R9).
// R10: 2-phase dbuf + counted vmcnt -> 134.5->120.5 us (verified R11).
// R11: DEPTH-2 PREFETCH, 3 buffers (48KB LDS). Depth-1 hid only ~1 iter
// (~130cyc) of the ~500-900cyc staging latency (still ~2000cyc/iter,
// MfmaUtil 24%). Now tile t+2 is issued at iter t top; vmcnt(8) waits only
// tile t (2 tiles x 4 loads remain in flight). Safety: the trailing barrier
// after COMPUTE(t-1) guarantees all ds_reads of b((t-1)%3) completed before
// any wave's STAGE(t+2) overwrites that buffer (same invariant as R10, one
// tile deeper). Tail peeled with vmcnt(4)/vmcnt(0).
// Epilogue: stride-132 bank pad; fb aliases dead staging buffers.
// ---------------------------------------------------------------------------
__global__ __launch_bounds__(256) void gemm_bt(
    const u16* __restrict__ A0, const u16* __restrict__ A1, int lda,
    const u16* __restrict__ Bt, int ldb,
    void* __restrict__ C, int ldc,
    int Mtiles, int K,
    const int* __restrict__ aselp, const int* __restrict__ ofp) {
    __shared__ char smem[49152];     // 3 x 16KB staging buffers

    const u16* A = aselp[0] ? A1 : A0;

    const int tid = threadIdx.x;
    const int w = tid >> 6, lane = tid & 63;
    const int Ntiles = gridDim.x / Mtiles;
    // XCD-chunked swizzle: xcd = bid & 7 owns tiles [xcd*q8, (xcd+1)*q8)
    const int q8 = gridDim.x >> 3;
    const int t  = (blockIdx.x & 7) * q8 + (blockIdx.x >> 3);
    const int mt = t / Ntiles;
    const int nt = t % Ntiles;
    const int m0 = mt << 7, n0 = nt << 7;
    const int wm = w >> 1, wn = w & 1;

    f32x4 acc[4][4] = {};

    // staging: row rr = w*16 + lane/4 (plus +64 for second store),
    // LDS slot s = lane&3 holds global chunk cg = s ^ swz(row), swz(r)=(r>>1)&3
    const int rr = w * 16 + (lane >> 2);
    const int cg = (lane & 3) ^ ((lane >> 3) & 3);

    const u16* gA0 = A + (m0 + rr) * lda + cg * 8;
    const u16* gA1 = A + (m0 + rr + 64) * lda + cg * 8;
    const u16* gB0 = Bt + (n0 + rr) * ldb + cg * 8;
    const u16* gB1 = Bt + (n0 + rr + 64) * ldb + cg * 8;

    // per-buffer LDS staging offsets (linear in lane)
    const int st0 = w * 1024 + lane * 16;

    // fragment reads: row = wm*64 + mi*16 + (lane&15), chunk q = lane>>4,
    // slot = q ^ ((lane>>1)&3)
    const int fr_a = (wm << 6) + (lane & 15);
    const int fr_b = (wn << 6) + (lane & 15);
    const int sl = (lane >> 4) ^ ((lane >> 1) & 3);
    const int offA = fr_a * 64 + sl * 16;
    const int offB = 8192 + fr_b * 64 + sl * 16;

#define STAGE(buf, kt) do {                                                        \
        char* sb_ = smem + (buf) * 16384;                                          \
        __builtin_amdgcn_global_load_lds((g_void*)(gA0 + (kt)),                    \
            (l_void*)(sb_ + st0), 16, 0, 0);                                       \
        __builtin_amdgcn_global_load_lds((g_void*)(gA1 + (kt)),                    \
            (l_void*)(sb_ + 4096 + st0), 16, 0, 0);                                \
        __builtin_amdgcn_global_load_lds((g_void*)(gB0 + (kt)),                    \
            (l_void*)(sb_ + 8192 + st0), 16, 0, 0);                                \
        __builtin_amdgcn_global_load_lds((g_void*)(gB1 + (kt)),                    \
            (l_void*)(sb_ + 12288 + st0), 16, 0, 0);                               \
    } while (0)

#define COMPUTE(buf) do {                                                          \
        const char* cb_ = smem + (buf) * 16384;                                    \
        short8 af[4], bfv[4];                                                      \
        _Pragma("unroll")                                                          \
        for (int i = 0; i < 4; ++i) {                                              \
            af[i]  = *(const short8*)(cb_ + offA + i * 1024);                      \
            bfv[i] = *(const short8*)(cb_ + offB + i * 1024);                      \
        }                                                                          \
        _Pragma("unroll")                                                          \
        for (int mi = 0; mi < 4; ++mi)                                             \
            _Pragma("unroll")                                                      \
            for (int ni = 0; ni < 4; ++ni)                                         \
                acc[mi][ni] = __builtin_amdgcn_mfma_f32_16x16x32_bf16(             \
                    af[mi], bfv[ni], acc[mi][ni], 0, 0, 0);                        \
    } while (0)

    const int ntiles = K >> 5;                       // 32 for K=1024
    STAGE(0, 0);
    STAGE(1, 32);
    int cc = 0, sc = 2;                              // compute buf, stage buf
    for (int i = 0; i < ntiles - 2; ++i) {
        STAGE(sc, (i + 2) << 5);                     // depth-2 prefetch
        asm volatile("s_waitcnt vmcnt(8)" ::: "memory");   // tile i done
        __builtin_amdgcn_s_barrier();
        __builtin_amdgcn_sched_barrier(0);
        COMPUTE(cc);
        __builtin_amdgcn_sched_barrier(0);
        __builtin_amdgcn_s_barrier();                // all waves done reading cc
        cc = (cc == 2) ? 0 : cc + 1;
        sc = (sc == 2) ? 0 : sc + 1;
    }
    // tail: two tiles remain in flight
    asm volatile("s_waitcnt vmcnt(4)" ::: "memory");
    __builtin_amdgcn_s_barrier();
    __builtin_amdgcn_sched_barrier(0);
    COMPUTE(cc);
    __builtin_amdgcn_sched_barrier(0);
    __builtin_amdgcn_s_barrier();
    cc = (cc == 2) ? 0 : cc + 1;
    asm volatile("s_waitcnt vmcnt(0)" ::: "memory");
    __builtin_amdgcn_s_barrier();
    __builtin_amdgcn_sched_barrier(0);
    COMPUTE(cc);
    __syncthreads();                                 // full drain before fb reuse

#undef STAGE
#undef COMPUTE

    // epilogue: repack 32-row strips through LDS (stride 132 = bank pad);
    // fully unrolled so every acc index is compile-time constant (rule #20).
    const int out_fp32 = ofp[0];
    float* fb = (float*)smem;
    const int lrow = tid >> 3, cgp = tid & 7;
#pragma unroll
    for (int mi = 0; mi < 4; ++mi) {
#pragma unroll
        for (int ni = 0; ni < 4; ++ni) {
#pragma unroll
            for (int r = 0; r < 4; ++r) {
                int lr = wm * 16 + ((lane >> 4) << 2) + r;
                int lc = wn * 64 + ni * 16 + (lane & 15);
                fb[lr * 132 + lc] = acc[mi][ni][r];
            }
        }
        __syncthreads();
        int grow = (lrow < 16) ? (mi * 16 + lrow) : (48 + mi * 16 + lrow);
        const float* srcp = fb + lrow * 132 + cgp * 16;
        if (out_fp32) {
            float4* dst = (float4*)((float*)C + (size_t)(m0 + grow) * ldc + n0 + cgp * 16);
            dst[0] = make_float4(srcp[0], srcp[1], srcp[2], srcp[3]);
            dst[1] = make_float4(srcp[4], srcp[5], srcp[6], srcp[7]);
            dst[2] = make_float4(srcp[8], srcp[9], srcp[10], srcp[11]);
            dst[3] = make_float4(srcp[12], srcp[13], srcp[14], srcp[15]);
        } else {
            u32 o0 = pack2(srcp[0], srcp[1]);
            u32 o1 = pack2(srcp[2], srcp[3]);
            u32 o2 = pack2(srcp[4], srcp[5]);
            u32 o3 = pack2(srcp[6], srcp[7]);
            u32 o4 = pack2(srcp[8], srcp[9]);
            u32 o5 = pack2(srcp[10], srcp[11]);
            u32 o6 = pack2(srcp[12], srcp[13]);
            u32 o7 = pack2(srcp[14], srcp[15]);
            uint4* dst = (uint4*)((u16*)C + (size_t)(m0 + grow) * ldc + n0 + cgp * 16);
            dst[0] = make_uint4(o0, o1, o2, o3);
            dst[1] = make_uint4(o4, o5, o6, o7);
        }
        __syncthreads();
    }
}

// ---------------------------------------------------------------------------
// Partial Kv/Ksum over 256-row chunks, NO max-shift (cancels in Kv/Ksum;
// |K| <~ 5 so fp32 exp is safe). Mask read dual-dtype from the raw input.
// Grid XCD-chunked (T1).
// ---------------------------------------------------------------------------
__global__ __launch_bounds__(256) void kvpart_kernel(const u16* __restrict__ QKV,
                                                     const void* __restrict__ mask,
                                                     const int* __restrict__ flags,
                                                     float* __restrict__ Kvp,
                                                     float* __restrict__ Ksp) {
    // XCD-chunked swizzle over 2048 blocks: t = xcd*256 + idx
    int t_ = (blockIdx.x & 7) * 256 + (blockIdx.x >> 3);
    int h = t_ & 15;
    int bc = t_ >> 4;                 // b*32 + chunk
    int chunk = bc & 31, b = bc >> 5;
    int w = threadIdx.x >> 6, lane = threadIdx.x & 63;
    int fp32m = flags[0];

    float kv[8] = {0, 0, 0, 0, 0, 0, 0, 0};
    float ks[8] = {0, 0, 0, 0, 0, 0, 0, 0};
    int t0 = chunk * 256;
    for (int i = 0; i < 64; ++i) {
        int t = t0 + w + i * 4;
        int m = b * 8192 + t;
        const u16* row = QKV + (size_t)m * 1280;
        float v = bf2f(row[256 + h * 64 + lane]);
        uint4 kq = *(const uint4*)(row + 128 + h * 8);
        float msk = fp32m ? ((const float*)mask)[m] : bf2f(((const u16*)mask)[m]);
        float vm = v * msk;
        float kf[8];
        kf[0] = __builtin_bit_cast(float, kq.x << 16);
        kf[1] = __builtin_bit_cast(float, kq.x & 0xffff0000u);
        kf[2] = __builtin_bit_cast(float, kq.y << 16);
        kf[3] = __builtin_bit_cast(float, kq.y & 0xffff0000u);
        kf[4] = __builtin_bit_cast(float, kq.z << 16);
        kf[5] = __builtin_bit_cast(float, kq.z & 0xffff0000u);
        kf[6] = __builtin_bit_cast(float, kq.w << 16);
        kf[7] = __builtin_bit_cast(float, kq.w & 0xffff0000u);
#pragma unroll
        for (int l = 0; l < 8; ++l) {
            float e = __expf(kf[l]) * msk;           // exp(K)*mask (no shift)
            kv[l] += e * vm;                         // * (V*mask)
            ks[l] += e;
        }
    }
    __shared__ float red[4][8][64];
    __shared__ float redks[4][8];
#pragma unroll
    for (int l = 0; l < 8; ++l) red[w][l][lane] = kv[l];
    if (lane == 0) {
#pragma unroll
        for (int l = 0; l < 8; ++l) redks[w][l] = ks[l];
    }
    __syncthreads();
    int tid = threadIdx.x;
    int obid = (b * 16 + h) * 32 + chunk;            // layout expected by kvreduce
    for (int c = tid; c < 512; c += 256) {
        int l = c >> 6, d = c & 63;
        Kvp[obid * 512 + c] = red[0][l][d] + red[1][l][d] + red[2][l][d] + red[3][l][d];
    }
    if (tid < 8) Ksp[obid * 8 + tid] = redks[0][tid] + redks[1][tid] + redks[2][tid] + redks[3][tid];
}

// 256 blocks x 128 threads.
__global__ void kvreduce_kernel(const float* __restrict__ Kvp, const float* __restrict__ Ksp,
                                float* __restrict__ Kv) {
    int bh = blockIdx.x >> 2;        // 64 bh values
    int seg = blockIdx.x & 3;
    int c0 = seg * 128 + threadIdx.x;   // element in [0,512)
    int l = c0 >> 6;
    float s = 0.f, ks = 0.f;
    for (int c = 0; c < 32; ++c) {
        s += Kvp[(bh * 32 + c) * 512 + c0];
        ks += Ksp[(bh * 32 + c) * 8 + l];
    }
    Kv[bh * 512 + c0] = s / ks;
}

// ---------------------------------------------------------------------------
// y[m, h*64+d] = softmax_l(Q[m,h,:]) @ Kv[b,h,l,d]; in-place over V region.
// 2048 blocks (16 rows/block): 8 blocks/CU for latency hiding.
// ---------------------------------------------------------------------------
__global__ __launch_bounds__(256) void y_kernel(u16* __restrict__ QKV,
                                                const float* __restrict__ Kv) {
    int bid = blockIdx.x;            // b*512 + chunk(16 rows)
    int b = bid >> 9, chunk = bid & 511;
    int w = threadIdx.x >> 6, lane = threadIdx.x & 63;
    int hh = w & 1;
    int rp = w >> 1;
    int hloc = lane >> 3;
    int h = hh * 8 + hloc;
    int dg = lane & 7;

    float4 kva[8], kvb[8];
    const float* kvp = Kv + (b * 16 + h) * 512 + dg * 8;
#pragma unroll
    for (int l = 0; l < 8; ++l) {
        kva[l] = *(const float4*)(kvp + l * 64);
        kvb[l] = *(const float4*)(kvp + l * 64 + 4);
    }
    int lgrp = lane & 56;
    for (int i = 0; i < 8; ++i) {
        int t = chunk * 16 + i * 2 + rp;
        int m = b * 8192 + t;
        u16* row = QKV + (size_t)m * 1280;
        float qv = bf2f(row[hh * 64 + lane]);
        float qm = qv;
        qm = fmaxf(qm, __shfl_xor(qm, 1));
        qm = fmaxf(qm, __shfl_xor(qm, 2));
        qm = fmaxf(qm, __shfl_xor(qm, 4));
        float e = __expf(qv - qm);
        float s = e;
        s += __shfl_xor(s, 1);
        s += __shfl_xor(s, 2);
        s += __shfl_xor(s, 4);
        float qs = e / s;
        float4 a0 = {0.f, 0.f, 0.f, 0.f}, a1 = {0.f, 0.f, 0.f, 0.f};
#pragma unroll
        for (int l = 0; l < 8; ++l) {
            float ql = __shfl(qs, lgrp + l);
            a0.x += ql * kva[l].x; a0.y += ql * kva[l].y;
            a0.z += ql * kva[l].z; a0.w += ql * kva[l].w;
            a1.x += ql * kvb[l].x; a1.y += ql * kvb[l].y;
            a1.z += ql * kvb[l].z; a1.w += ql * kvb[l].w;
        }
        uint4 o;
        o.x = pack2(a0.x, a0.y);
        o.y = pack2(a0.z, a0.w);
        o.z = pack2(a1.x, a1.y);
        o.w = pack2(a1.z, a1.w);
        *(uint4*)(row + 256 + h * 64 + dg * 8) = o;
    }
}

// ---------------------------------------------------------------------------
// Workspace layout (bytes).
// ---------------------------------------------------------------------------
#define OFF_FLAG ((size_t)0)                        // 2 ints
#define OFF_W1T  ((size_t)1024)                     // 1280*1024*2 = 2,621,440
#define OFF_OPT  ((size_t)2622464)                  // 1024*1024*2 = 2,097,152
#define OFF_KVP  ((size_t)4787200)                  // 2048*512*4 = 4,194,304
#define OFF_KSP  ((size_t)8981504)                  // 2048*8*4 = 65,536
#define OFF_KV   ((size_t)9047040)                  // 64*512*4 = 131,072
#define OFF_XC   ((size_t)9309184)                  // 33554432*2 = 67,108,864
#define OFF_QKV  ((size_t)76418048)                 // 32768*1280*2 = 83,886,080
// total = 160,304,128 bytes

extern "C" void kernel_launch(void* const* d_in, const int* in_sizes, int n_in,
                              void* d_out, int out_size, void* d_ws, size_t ws_size,
                              hipStream_t stream) {
    const u16* X   = (const u16*)d_in[0];
    const void* msk = d_in[1];
    const void* Wk  = d_in[2];
    const void* Wq  = d_in[3];
    const void* Wv  = d_in[4];
    const void* Op  = d_in[5];

    char* ws = (char*)d_ws;
    int*   FLAGS = (int*)(ws + OFF_FLAG);
    u16*   W1T  = (u16*)(ws + OFF_W1T);
    u16*   OPT  = (u16*)(ws + OFF_OPT);
    float* KVP  = (float*)(ws + OFF_KVP);
    float* KSP  = (float*)(ws + OFF_KSP);
    float* KV   = (float*)(ws + OFF_KV);
    u16*   XC   = (u16*)(ws + OFF_XC);
    u16*   QKV  = (u16*)(ws + OFF_QKV);

    // 0) detect input dtype (flags[0]=1 -> fp32), flags[1]=0 always
    detect_kernel<<<1, 256, 0, stream>>>(X, FLAGS);
    // 1) fused: X canonicalization + weight transposes (one launch)
    prep_kernel<<<18688, 256, 0, stream>>>((const float*)d_in[0], XC,
                                           Wq, Wk, Wv, Op, W1T, OPT, FLAGS);
    // 2) fused QKV projection: QKV[m,0:128)=Q, [128:256)=K, [256:1280)=V
    gemm_bt<<<2560, 256, 0, stream>>>(X, XC, 1024, W1T, 1024, QKV, 1280, 256, 1024,
                                      FLAGS, FLAGS + 1);
    // 3) Kv state + Ksum (no max pass -- it cancels in Kv/Ksum)
    kvpart_kernel<<<2048, 256, 0, stream>>>(QKV, msk, FLAGS, KVP, KSP);
    kvreduce_kernel<<<256, 128, 0, stream>>>(KVP, KSP, KV);
    // 4) y = softmax(Q) @ Kv, in-place over V region
    y_kernel<<<2048, 256, 0, stream>>>(QKV, KV);
    // 5) out = y @ o_proj (output dtype per detected flag)
    gemm_bt<<<2048, 256, 0, stream>>>(QKV + 256, QKV + 256, 1280, OPT, 1024,
                                      d_out, 1024, 256, 1024, FLAGS + 1, FLAGS);
}